// Round 1
// 289.812 us; speedup vs baseline: 1.1104x; 1.1104x over previous
//
#include <hip/hip_runtime.h>

// ---------------------------------------------------------------------------
// Bidirectional Mamba block, MI355X. Round 21:
//  - kconv3 rewritten as bf16 implicit-GEMM on MFMA (16x16x32, fp32 accum):
//    27 shifted 64x64 GEMMs over a zero-padded LDS halo tile, ci-contiguous.
//    Was fp32 VALU-bound at 34% of 157TF (MfmaUtil=0, 68.6us); matrix pipe
//    ceiling is ~16x higher.
//  - kprepw: one-time weight transpose/bf16-cast to Wbf[27][co][ci] in slab0
//    OO scratch (dead after kscanC).
//  - kconv3 now computes all 64 ci per block -> writes FINAL conv+bias+resid
//    to OX4 only; knorm reads a single buffer (was 4-partial sum).
// Shapes: B=4, C=64, D=128, L=4096 (l = h*256 + w*16 + t), N=16, R=8.
// ---------------------------------------------------------------------------

#define NL 4096

typedef unsigned short u16;
typedef unsigned int u32;
typedef __attribute__((ext_vector_type(8))) short bf16x8;
typedef __attribute__((ext_vector_type(4))) float f32x4;

__device__ __forceinline__ float siluf_(float x) { return x / (1.f + __expf(-x)); }
__device__ __forceinline__ float softplusf_(float x) {
  return (x > 20.f) ? x : log1pf(__expf(x));
}
__device__ __forceinline__ u16 f2bf(float f) {
  u32 u = __float_as_uint(f);
  u += 0x7fffu + ((u >> 16) & 1u);
  return (u16)(u >> 16);
}
__device__ __forceinline__ float bflo(u32 v) { return __uint_as_float(v << 16); }
__device__ __forceinline__ float bfhi(u32 v) { return __uint_as_float(v & 0xFFFF0000u); }

// Sum over the 16-lane DPP row via rotations 1,2,4,8 (VALU pipe, no DS).
__device__ __forceinline__ float rowsum16_(float p) {
  int q;
  q = __builtin_amdgcn_mov_dpp(__float_as_int(p), 0x121, 0xf, 0xf, false);
  p += __int_as_float(q);
  q = __builtin_amdgcn_mov_dpp(__float_as_int(p), 0x122, 0xf, 0xf, false);
  p += __int_as_float(q);
  q = __builtin_amdgcn_mov_dpp(__float_as_int(p), 0x124, 0xf, 0xf, false);
  p += __int_as_float(q);
  q = __builtin_amdgcn_mov_dpp(__float_as_int(p), 0x128, 0xf, 0xf, false);
  p += __int_as_float(q);
  return p;
}

// Per-b slab offsets (fp32 elements; bf16 regions use u16 views at same base)
#define OXZ  0u          // xz [256][4096] fp32
#define OUCF 1048576u    // ucf [128][4096] bf16 (u16 view)
#define OUCB 1572864u    // ucb [128][4096] bf16 (flipped coords)
#define ODLF 2424832u    // dlf [128][4096] bf16
#define ODLB 2949120u    // dlb [128][4096] bf16 (flipped coords)
#define OYF  3473408u    // yf [128][4096] fp32
#define OYB  3997696u    // yb [128][4096] fp32 (flipped coords)
#define OO   4521984u    // scan scratch P/S; after kscanC: slab0 holds Wbf bf16
#define OO2  5046272u    // bct bf16 until kscanC; then o2 [4096][64] fp32
#define OX4  5308416u    // conv3 final output (+bias+residual)
#define PER_B 5570560u

#define NCH 64   // scan chunks
#define CL  64   // chunk length

// 1. xz[e,l] = sum_c in_proj_w[e,c] * seq[c,l].
__global__ __launch_bounds__(256) void kxz(
    const float* __restrict__ x, const float* __restrict__ wip,
    float* __restrict__ ws, int b0) {
  int bi = blockIdx.y, gb = b0 + bi;
  float* s = ws + (size_t)bi * PER_B;
  int bid = blockIdx.x;
  int h = bid >> 4, w = bid & 15;
  int tid = threadIdx.x;
  __shared__ float xs[64][16];
  for (int i = tid; i < 1024; i += 256) {
    int c = i >> 4, t = i & 15;
    xs[c][t] = x[(size_t)(gb * 64 + c) * NL + t * 256 + h * 16 + w];
  }
  __syncthreads();
  int e = tid;
  float acc[16];
#pragma unroll
  for (int t = 0; t < 16; ++t) acc[t] = 0.f;
  for (int c = 0; c < 64; ++c) {
    float wv = wip[e * 64 + c];
#pragma unroll
    for (int t = 0; t < 16; ++t) acc[t] = fmaf(wv, xs[c][t], acc[t]);
  }
  float4* dst = (float4*)(s + OXZ + (size_t)e * NL + h * 256 + w * 16);
#pragma unroll
  for (int q = 0; q < 4; ++q)
    dst[q] = make_float4(acc[q * 4], acc[q * 4 + 1], acc[q * 4 + 2], acc[q * 4 + 3]);
}

// 2. Fused prep per (bi, 32-l tile): dwconv+silu, x_dbl (float4), delta, bct.
__global__ __launch_bounds__(256) void k2prep(
    const float* __restrict__ cwf, const float* __restrict__ cbf,
    const float* __restrict__ xpf, const float* __restrict__ dtwf,
    const float* __restrict__ dtbf,
    const float* __restrict__ cwb, const float* __restrict__ cbb,
    const float* __restrict__ xpb, const float* __restrict__ dtwb,
    const float* __restrict__ dtbb,
    float* __restrict__ ws) {
  int bi = blockIdx.y;
  float* s = ws + (size_t)bi * PER_B;
  int lt = blockIdx.x;
  int l0 = lt * 32;
  int l0b = (127 - lt) * 32;
  int tid = threadIdx.x;

  __shared__ float pool[128 * 40];   // X[128][40] during dwconv; xds after
  __shared__ float ucs[2][128][32];
  float (*X)[40] = (float(*)[40])pool;

  for (int i = tid; i < 128 * 38; i += 256) {
    int d = i / 38, j = i - d * 38;
    int l = l0 - 3 + j;
    X[d][j] = (l >= 0 && l < NL) ? s[OXZ + (size_t)d * NL + l] : 0.f;
  }
  __syncthreads();

  u16* ucfp = (u16*)(s + OUCF);
  u16* ucbp = (u16*)(s + OUCB);
  for (int i = tid; i < 2 * 128 * 32; i += 256) {
    int br = i >> 12, rem = i & 4095;
    int d = rem >> 5, li = rem & 31;
    float a;
    if (br == 0) {
      a = cbf[d];
#pragma unroll
      for (int k = 0; k < 4; ++k) a = fmaf(cwf[d * 4 + k], X[d][li + k], a);
    } else {
      a = cbb[d];
#pragma unroll
      for (int k = 0; k < 4; ++k) a = fmaf(cwb[d * 4 + k], X[d][37 - li - k], a);
    }
    a = siluf_(a);
    ucs[br][d][li] = a;
    int lg = br ? (l0b + li) : (l0 + li);
    (br ? ucbp : ucfp)[(size_t)d * NL + lg] = f2bf(a);
  }
  __syncthreads();  // X dead; pool becomes xds [2][40][33]

  float* xds = pool;
  for (int i = tid; i < 640; i += 256) {
    int br = i / 320;
    int rem = i - br * 320;
    int e = rem >> 3, liq = rem & 7;
    const float* xp = br ? xpb : xpf;
    float4 acc = make_float4(0.f, 0.f, 0.f, 0.f);
    for (int d = 0; d < 128; ++d) {
      float wv = xp[e * 128 + d];
      const float4 u4 = *(const float4*)&ucs[br][d][liq * 4];
      acc.x = fmaf(wv, u4.x, acc.x);
      acc.y = fmaf(wv, u4.y, acc.y);
      acc.z = fmaf(wv, u4.z, acc.z);
      acc.w = fmaf(wv, u4.w, acc.w);
    }
    float* dst = &xds[(br * 40 + e) * 33 + liq * 4];
    dst[0] = acc.x; dst[1] = acc.y; dst[2] = acc.z; dst[3] = acc.w;
  }
  __syncthreads();

  u16* dlfp = (u16*)(s + ODLF);
  u16* dlbp = (u16*)(s + ODLB);
  for (int i = tid; i < 2 * 128 * 32; i += 256) {
    int br = i >> 12, rem = i & 4095;
    int d = rem >> 5, li = rem & 31;
    const float* dtw = br ? dtwb : dtwf;
    float pre = (br ? dtbb : dtbf)[d];
#pragma unroll
    for (int r = 0; r < 8; ++r)
      pre = fmaf(dtw[d * 8 + r], xds[(br * 40 + r) * 33 + li], pre);
    int lg = br ? (l0b + li) : (l0 + li);
    (br ? dlbp : dlfp)[(size_t)d * NL + lg] = f2bf(softplusf_(pre));
  }
  u16* bctp = (u16*)(s + OO2);
  for (int i = tid; i < 2 * 32 * 32; i += 256) {
    int dir = i >> 10;
    int li = (i >> 5) & 31, k = i & 31;
    int lg = dir ? (l0b + li) : (l0 + li);
    bctp[((size_t)dir * 4096 + lg) * 32 + k] = f2bf(xds[(dir * 40 + 8 + k) * 33 + li]);
  }
}

// 5a. Phase A: 16 d-rows/block; chunk bct (bf16) staged to fp32 LDS;
// ushort8 dl/uc loads = 8 steps per load pair.
__global__ __launch_bounds__(256) void kscanA(
    const float* __restrict__ Alf, const float* __restrict__ Alb,
    float* __restrict__ ws) {
  int bi = blockIdx.y;
  float* s = ws + (size_t)bi * PER_B;
  int xid = blockIdx.x;
  int chunk = xid >> 4, dir = (xid >> 3) & 1, d8 = xid & 7;
  int tid = threadIdx.x;
  int wv = tid >> 6, lane = tid & 63;
  int n = lane & 15, g = lane >> 4;
  int d = d8 * 16 + wv * 4 + g;
  int l0 = chunk * CL;
  __shared__ float bl[CL * 32];
  {
    const u16* bctp = (const u16*)(s + OO2) + ((size_t)dir * 4096 + l0) * 32;
    for (int i = tid; i < CL * 32; i += 256)
      bl[i] = __uint_as_float(((u32)bctp[i]) << 16);
  }
  __syncthreads();
  const u16* ucp = (const u16*)(s + (dir ? OUCB : OUCF)) + (size_t)d * NL + l0;
  const u16* dlp = (const u16*)(s + (dir ? ODLB : ODLF)) + (size_t)d * NL + l0;
  float A = -__expf((dir ? Alb : Alf)[d * 16 + n]);
  float P = 1.f, S = 0.f;
  for (int i0 = 0; i0 < CL; i0 += 8) {
    uint4 dq = *(const uint4*)(dlp + i0);
    uint4 uq = *(const uint4*)(ucp + i0);
    float dv[8] = {bflo(dq.x), bfhi(dq.x), bflo(dq.y), bfhi(dq.y),
                   bflo(dq.z), bfhi(dq.z), bflo(dq.w), bfhi(dq.w)};
    float uv[8] = {bflo(uq.x), bfhi(uq.x), bflo(uq.y), bfhi(uq.y),
                   bflo(uq.z), bfhi(uq.z), bflo(uq.w), bfhi(uq.w)};
#pragma unroll
    for (int j = 0; j < 8; ++j) {
      float dA = __expf(dv[j] * A);
      S = fmaf(dA, S, dv[j] * bl[(i0 + j) * 32 + n] * uv[j]);
      P *= dA;
    }
  }
  size_t cidx = ((size_t)(chunk * 2 + dir) * 128 + d) * 16 + n;
  s[OO + cidx] = P;
  s[OO + 262144u + cidx] = S;
}

// 5b. Phase B: carry combine.
__global__ __launch_bounds__(64) void kscanB(float* __restrict__ ws) {
  int bi = blockIdx.y;
  float* s = ws + (size_t)bi * PER_B;
  int dir = blockIdx.x >> 5, dblk = blockIdx.x & 31;
  int tid = threadIdx.x;
  size_t base = (size_t)dir * 2048 + dblk * 64 + tid;
  float carry = 0.f;
#pragma unroll 4
  for (int c = 0; c < NCH; ++c) {
    size_t idx = (size_t)c * 4096 + base;
    float pv = s[OO + idx], sv = s[OO + 262144u + idx];
    s[OO + 262144u + idx] = carry;
    carry = fmaf(pv, carry, sv);
  }
}

// 5c. Phase C: seeded re-scan; bf16 inputs; DPP row-sum; ps[16][65] staging.
__global__ __launch_bounds__(256) void kscanC(
    const float* __restrict__ Alf, const float* __restrict__ Df,
    const float* __restrict__ Alb, const float* __restrict__ Db,
    float* __restrict__ ws) {
  int bi = blockIdx.y;
  float* s = ws + (size_t)bi * PER_B;
  int xid = blockIdx.x;
  int chunk = xid >> 4, dir = (xid >> 3) & 1, d8 = xid & 7;
  int tid = threadIdx.x;
  int wv = tid >> 6, lane = tid & 63;
  int n = lane & 15, g = lane >> 4;
  int d = d8 * 16 + wv * 4 + g;
  int l0 = chunk * CL;
  __shared__ float bl[CL * 32];
  __shared__ float ps[16][65];
  {
    const u16* bctp = (const u16*)(s + OO2) + ((size_t)dir * 4096 + l0) * 32;
    for (int i = tid; i < CL * 32; i += 256)
      bl[i] = __uint_as_float(((u32)bctp[i]) << 16);
  }
  __syncthreads();
  const u16* ucp = (const u16*)(s + (dir ? OUCB : OUCF)) + (size_t)d * NL + l0;
  const u16* dlp = (const u16*)(s + (dir ? ODLB : ODLF)) + (size_t)d * NL + l0;
  float* ybase = s + (dir ? OYB : OYF);
  float A = -__expf((dir ? Alb : Alf)[d * 16 + n]);
  float Dv = (dir ? Db : Df)[d];
  size_t cidx = ((size_t)(chunk * 2 + dir) * 128 + d) * 16 + n;
  float h = s[OO + 262144u + cidx];
  int prow = wv * 4 + g;
  for (int i0 = 0; i0 < CL; i0 += 8) {
    uint4 dq = *(const uint4*)(dlp + i0);
    uint4 uq = *(const uint4*)(ucp + i0);
    float dv[8] = {bflo(dq.x), bfhi(dq.x), bflo(dq.y), bfhi(dq.y),
                   bflo(dq.z), bfhi(dq.z), bflo(dq.w), bfhi(dq.w)};
    float uv[8] = {bflo(uq.x), bfhi(uq.x), bflo(uq.y), bfhi(uq.y),
                   bflo(uq.z), bfhi(uq.z), bflo(uq.w), bfhi(uq.w)};
#pragma unroll
    for (int j = 0; j < 8; ++j) {
      int i = i0 + j;
      float dA = __expf(dv[j] * A);
      h = fmaf(dA, h, dv[j] * bl[i * 32 + n] * uv[j]);
      float p = rowsum16_(h * bl[i * 32 + 16 + n]);
      if (n == 0) ps[prow][i] = fmaf(uv[j], Dv, p);
    }
  }
  __syncthreads();
  for (int i = tid; i < 16 * CL; i += 256) {
    int row = i >> 6, col = i & 63;
    ybase[(size_t)(d8 * 16 + row) * NL + l0 + col] = ps[row][col];
  }
}

// 6. Fused gate + out-proj. Block = 32-l tile.
__global__ __launch_bounds__(256) void koutg(
    const float* __restrict__ wout, float* __restrict__ ws) {
  int bi = blockIdx.y;
  float* s = ws + (size_t)bi * PER_B;
  int lt = blockIdx.x;
  int l0 = lt * 32;
  int tid = threadIdx.x;
  __shared__ float ot[128][32];
  __shared__ float ot2[64][33];
  for (int i = tid; i < 128 * 32; i += 256) {
    int d = i >> 5, li = i & 31;
    int l = l0 + li;
    float z = s[OXZ + (size_t)(128 + d) * NL + l];
    float v = s[OYF + (size_t)d * NL + l] + s[OYB + (size_t)d * NL + (NL - 1 - l)];
    ot[d][li] = v * siluf_(z);
  }
  __syncthreads();
  {
    int li = tid & 31, cg = tid >> 5;
    float acc[8];
#pragma unroll
    for (int j = 0; j < 8; ++j) acc[j] = 0.f;
    for (int d4 = 0; d4 < 128; d4 += 4) {
      float o0 = ot[d4][li], o1 = ot[d4 + 1][li];
      float o2v = ot[d4 + 2][li], o3 = ot[d4 + 3][li];
#pragma unroll
      for (int j = 0; j < 8; ++j) {
        float4 w4 = *(const float4*)&wout[(cg * 8 + j) * 128 + d4];
        acc[j] = fmaf(w4.x, o0, fmaf(w4.y, o1, fmaf(w4.z, o2v, fmaf(w4.w, o3, acc[j]))));
      }
    }
#pragma unroll
    for (int j = 0; j < 8; ++j) ot2[cg * 8 + j][li] = acc[j];
  }
  __syncthreads();
  for (int i = tid; i < 32 * 64; i += 256) {
    int li = i >> 6, c = i & 63;
    s[OO2 + (size_t)(l0 + li) * 64 + c] = ot2[c][li];
  }
}

// 6.5. Weight prep: Wbf[27][co 64][ci 64] bf16 into slab0's OO scratch
// (dead after kscanC). 27 blocks, one per tap.
__global__ __launch_bounds__(256) void kprepw(
    const float* __restrict__ pw, float* __restrict__ ws) {
  int off = blockIdx.x;
  u16* wb = (u16*)(ws + OO);
  int tid = threadIdx.x;
  for (int i = tid; i < 4096; i += 256) {
    int co = i >> 6, ci = i & 63;
    wb[off * 4096 + i] = f2bf(pw[(size_t)(co * 64 + ci) * 27 + off]);
  }
}

// 7. conv3d as bf16 implicit GEMM on MFMA (fp32 accum). Block tile
// [64 co][64 l] = one t-plane x 4 h-rows; grid = t(16) x hq(4) = 64/slab.
// LDS: zero-padded halo Xs[tt 3][hh 6][ww 18][ci 64 pad 72] bf16 (46.6 KB),
// ci-contiguous so B-frags are single ds_read_b128 of 8 ci.
// Wave (of 4) = [32 co][32 l]; per K-step: 2 A global 16B loads (Wbf, L1/L2
// resident) + 2 ds_read_b128 + 4 mfma_f32_16x16x32_bf16. 54 K-steps.
// Writes FINAL conv + bias + residual to OX4 (no more 4-partial scheme).
__global__ __launch_bounds__(256) void kconv3(
    const float* __restrict__ pb, const float* __restrict__ xin,
    float* __restrict__ ws, int b0) {
  int bi = blockIdx.y, gb = b0 + bi;
  float* s = ws + (size_t)bi * PER_B;
  int t = blockIdx.x >> 2, hq = blockIdx.x & 3;
  int h0 = hq * 4;
  int tid = threadIdx.x;
  const u16* wb = (const u16*)(ws + OO);  // slab0 weights (shared)
  const float* xr = s + OO2;              // o2 in c'-major view [64][4096]

  __shared__ u16 Xs[3 * 6 * 18 * 72];
  // zero (covers t/h/w halo padding)
  {
    u32* xz32 = (u32*)Xs;
    for (int i = tid; i < 3 * 6 * 18 * 72 / 2; i += 256) xz32[i] = 0u;
  }
  __syncthreads();
  // stage valid rows, transposed to ci-contiguous bf16
  {
    int ci = tid >> 2, wq = tid & 3;
    for (int row = 0; row < 18; ++row) {
      int tt = row / 6, hh = row - tt * 6;
      int ts = t + tt - 1, hs = h0 + hh - 1;
      if (ts < 0 || ts > 15 || hs < 0 || hs > 15) continue;
      float4 v = *(const float4*)(xr + (size_t)ci * NL + ts * 256 + hs * 16 + wq * 4);
      int rb = (tt * 6 + hh) * 18 + 1 + wq * 4;
      Xs[(rb + 0) * 72 + ci] = f2bf(v.x);
      Xs[(rb + 1) * 72 + ci] = f2bf(v.y);
      Xs[(rb + 2) * 72 + ci] = f2bf(v.z);
      Xs[(rb + 3) * 72 + ci] = f2bf(v.w);
    }
  }
  __syncthreads();

  int wid = tid >> 6, lane = tid & 63;
  int cb = wid >> 1, lb = wid & 1;
  int n16 = lane & 15, kg = lane >> 4;   // k-group 0..3 (8 ci each)
  f32x4 acc[2][2] = {};                  // [c2 co-subtile][l2 l-subtile]

  // A: Wbf[off][co][ci]; lane row co = cb*32 + c2*16 + n16, k = kg*8+st*32+j
  const u16* wbA = wb + (size_t)(cb * 32 + n16) * 64 + kg * 8;
  for (int kt = 0; kt < 3; ++kt)
    for (int kh = 0; kh < 3; ++kh) {
      int rbase = (kt * 6 + lb * 2 + kh) * 18 + n16;
#pragma unroll
      for (int kw = 0; kw < 3; ++kw) {
        int off = (kt * 3 + kh) * 3 + kw;
        int r0 = rbase + kw;       // l2=0 spatial row
        const u16* pa = wbA + off * 4096;
#pragma unroll
        for (int st = 0; st < 2; ++st) {
          int kb = st * 32;
          bf16x8 a0 = *(const bf16x8*)(pa + kb);
          bf16x8 a1 = *(const bf16x8*)(pa + 16 * 64 + kb);
          bf16x8 b0 = *(const bf16x8*)(&Xs[r0 * 72 + kb + kg * 8]);
          bf16x8 b1 = *(const bf16x8*)(&Xs[(r0 + 18) * 72 + kb + kg * 8]);
          acc[0][0] = __builtin_amdgcn_mfma_f32_16x16x32_bf16(a0, b0, acc[0][0], 0, 0, 0);
          acc[0][1] = __builtin_amdgcn_mfma_f32_16x16x32_bf16(a0, b1, acc[0][1], 0, 0, 0);
          acc[1][0] = __builtin_amdgcn_mfma_f32_16x16x32_bf16(a1, b0, acc[1][0], 0, 0, 0);
          acc[1][1] = __builtin_amdgcn_mfma_f32_16x16x32_bf16(a1, b1, acc[1][1], 0, 0, 0);
        }
      }
    }

  // C/D layout: col = lane&15 (w), row = kg*4 + reg (co within 16-subtile)
#pragma unroll
  for (int c2 = 0; c2 < 2; ++c2) {
#pragma unroll
    for (int l2 = 0; l2 < 2; ++l2) {
      int lg = t * 256 + (h0 + lb * 2 + l2) * 16 + n16;
#pragma unroll
      for (int rg = 0; rg < 4; ++rg) {
        int co = cb * 32 + c2 * 16 + kg * 4 + rg;
        float v = acc[c2][l2][rg] + pb[co] +
                  xin[(size_t)(gb * 64 + co) * NL + lg];
        s[OX4 + (size_t)co * NL + lg] = v;
      }
    }
  }
}

// 8. knorm: LDS-tiled 1x1x1 mix over the single conv3 output + norm_b.
__global__ __launch_bounds__(256) void knorm(
    const float* __restrict__ nw, const float* __restrict__ nb,
    float* __restrict__ out, float* __restrict__ ws, int b0) {
  int bi = blockIdx.y, gb = b0 + bi;
  float* s = ws + (size_t)bi * PER_B;
  int pt = blockIdx.x;
  int p0 = pt * 64;
  int tid = threadIdx.x;
  __shared__ float xs[64][64];
  for (int i = tid; i < 4096; i += 256) {
    int ci = i >> 6, p = i & 63;
    xs[ci][p] = s[OX4 + (size_t)ci * NL + p0 + p];
  }
  __syncthreads();
  int co = tid >> 2, pq = tid & 3;
  float acc[16];
#pragma unroll
  for (int j = 0; j < 16; ++j) acc[j] = 0.f;
  for (int ci = 0; ci < 64; ci += 4) {
    float4 w4 = *(const float4*)&nw[co * 64 + ci];
    float wv[4] = {w4.x, w4.y, w4.z, w4.w};
#pragma unroll
    for (int cc = 0; cc < 4; ++cc) {
      const float4* row = (const float4*)&xs[ci + cc][pq * 16];
      float4 a = row[0], b = row[1], c = row[2], e = row[3];
      acc[0] = fmaf(wv[cc], a.x, acc[0]);  acc[1] = fmaf(wv[cc], a.y, acc[1]);
      acc[2] = fmaf(wv[cc], a.z, acc[2]);  acc[3] = fmaf(wv[cc], a.w, acc[3]);
      acc[4] = fmaf(wv[cc], b.x, acc[4]);  acc[5] = fmaf(wv[cc], b.y, acc[5]);
      acc[6] = fmaf(wv[cc], b.z, acc[6]);  acc[7] = fmaf(wv[cc], b.w, acc[7]);
      acc[8] = fmaf(wv[cc], c.x, acc[8]);  acc[9] = fmaf(wv[cc], c.y, acc[9]);
      acc[10] = fmaf(wv[cc], c.z, acc[10]); acc[11] = fmaf(wv[cc], c.w, acc[11]);
      acc[12] = fmaf(wv[cc], e.x, acc[12]); acc[13] = fmaf(wv[cc], e.y, acc[13]);
      acc[14] = fmaf(wv[cc], e.z, acc[14]); acc[15] = fmaf(wv[cc], e.w, acc[15]);
    }
  }
  float bias = nb[co];
  float4* dst = (float4*)(out + (size_t)(gb * 64 + co) * NL + p0 + pq * 16);
#pragma unroll
  for (int q = 0; q < 4; ++q)
    dst[q] = make_float4(acc[q * 4] + bias, acc[q * 4 + 1] + bias,
                         acc[q * 4 + 2] + bias, acc[q * 4 + 3] + bias);
}

// ---------------------------------------------------------------------------
extern "C" void kernel_launch(void* const* d_in, const int* in_sizes, int n_in,
                              void* d_out, int out_size, void* d_ws, size_t ws_size,
                              hipStream_t stream) {
  const float* x    = (const float*)d_in[0];
  const float* wip  = (const float*)d_in[1];
  const float* cwf  = (const float*)d_in[2];
  const float* cbf  = (const float*)d_in[3];
  const float* xpf  = (const float*)d_in[4];
  const float* dtwf = (const float*)d_in[5];
  const float* dtbf = (const float*)d_in[6];
  const float* Alf  = (const float*)d_in[7];
  const float* Df   = (const float*)d_in[8];
  const float* cwb  = (const float*)d_in[9];
  const float* cbb  = (const float*)d_in[10];
  const float* xpb  = (const float*)d_in[11];
  const float* dtwb = (const float*)d_in[12];
  const float* dtbb = (const float*)d_in[13];
  const float* Alb  = (const float*)d_in[14];
  const float* Db   = (const float*)d_in[15];
  const float* wout = (const float*)d_in[16];
  const float* pw   = (const float*)d_in[17];
  const float* pb   = (const float*)d_in[18];
  const float* nw   = (const float*)d_in[19];
  const float* nb   = (const float*)d_in[20];

  const size_t PER_B_BYTES = (size_t)PER_B * 4;  // 22,282,240 per batch slab
  int bcnt;
  if (ws_size >= 4 * PER_B_BYTES) bcnt = 4;
  else if (ws_size >= PER_B_BYTES) bcnt = 1;
  else return;
  int passes = 4 / bcnt;

  float* ws = (float*)d_ws;
  for (int p = 0; p < passes; ++p) {
    int b0 = p * bcnt;
    kxz   <<<dim3(256, bcnt), 256, 0, stream>>>(x, wip, ws, b0);
    k2prep<<<dim3(128, bcnt), 256, 0, stream>>>(cwf, cbf, xpf, dtwf, dtbf,
                                                cwb, cbb, xpb, dtwb, dtbb, ws);
    kscanA<<<dim3(1024, bcnt), 256, 0, stream>>>(Alf, Alb, ws);
    kscanB<<<dim3(64, bcnt), 64, 0, stream>>>(ws);
    kscanC<<<dim3(1024, bcnt), 256, 0, stream>>>(Alf, Df, Alb, Db, ws);
    koutg <<<dim3(128, bcnt), 256, 0, stream>>>(wout, ws);
    kprepw<<<dim3(27), 256, 0, stream>>>(pw, ws);
    kconv3<<<dim3(64, bcnt), 256, 0, stream>>>(pb, x, ws, b0);
    knorm <<<dim3(64, bcnt), 256, 0, stream>>>(nw, nb, (float*)d_out, ws, b0);
  }
}

// Round 2
// 285.022 us; speedup vs baseline: 1.1291x; 1.0168x over previous
//
#include <hip/hip_runtime.h>

// ---------------------------------------------------------------------------
// Bidirectional Mamba block, MI355X. Round 22:
//  - k2prep x_dbl phase (xds = xp @ uc, E40 L32 K128 x2dir) rewritten as MFMA:
//    was a 640-item serial fp32 loop (latency-bound, 85% of k2prep's 55us).
//    dwconv now stores uc transposed bf16 in LDS (uct[br][l][d+pad], ci-
//    contiguous) -> B-frags are single ds_read_b128; A-frags packed from fp32
//    xproj weights in regs (L1-resident). LDS 53KB->38KB (4 blocks/CU).
//  - kconv3: bf16 implicit-GEMM on MFMA (R21, verified).
// Shapes: B=4, C=64, D=128, L=4096 (l = h*256 + w*16 + t), N=16, R=8.
// ---------------------------------------------------------------------------

#define NL 4096

typedef unsigned short u16;
typedef unsigned int u32;
typedef __attribute__((ext_vector_type(8))) short bf16x8;
typedef __attribute__((ext_vector_type(4))) float f32x4;

__device__ __forceinline__ float siluf_(float x) { return x / (1.f + __expf(-x)); }
__device__ __forceinline__ float softplusf_(float x) {
  return (x > 20.f) ? x : log1pf(__expf(x));
}
__device__ __forceinline__ u16 f2bf(float f) {
  u32 u = __float_as_uint(f);
  u += 0x7fffu + ((u >> 16) & 1u);
  return (u16)(u >> 16);
}
__device__ __forceinline__ float bflo(u32 v) { return __uint_as_float(v << 16); }
__device__ __forceinline__ float bfhi(u32 v) { return __uint_as_float(v & 0xFFFF0000u); }

// Sum over the 16-lane DPP row via rotations 1,2,4,8 (VALU pipe, no DS).
__device__ __forceinline__ float rowsum16_(float p) {
  int q;
  q = __builtin_amdgcn_mov_dpp(__float_as_int(p), 0x121, 0xf, 0xf, false);
  p += __int_as_float(q);
  q = __builtin_amdgcn_mov_dpp(__float_as_int(p), 0x122, 0xf, 0xf, false);
  p += __int_as_float(q);
  q = __builtin_amdgcn_mov_dpp(__float_as_int(p), 0x124, 0xf, 0xf, false);
  p += __int_as_float(q);
  q = __builtin_amdgcn_mov_dpp(__float_as_int(p), 0x128, 0xf, 0xf, false);
  p += __int_as_float(q);
  return p;
}

// Per-b slab offsets (fp32 elements; bf16 regions use u16 views at same base)
#define OXZ  0u          // xz [256][4096] fp32
#define OUCF 1048576u    // ucf [128][4096] bf16 (u16 view)
#define OUCB 1572864u    // ucb [128][4096] bf16 (flipped coords)
#define ODLF 2424832u    // dlf [128][4096] bf16
#define ODLB 2949120u    // dlb [128][4096] bf16 (flipped coords)
#define OYF  3473408u    // yf [128][4096] fp32
#define OYB  3997696u    // yb [128][4096] fp32 (flipped coords)
#define OO   4521984u    // scan scratch P/S; after kscanC: slab0 holds Wbf bf16
#define OO2  5046272u    // bct bf16 until kscanC; then o2 [4096][64] fp32
#define OX4  5308416u    // conv3 final output (+bias+residual)
#define PER_B 5570560u

#define NCH 64   // scan chunks
#define CL  64   // chunk length

// 1. xz[e,l] = sum_c in_proj_w[e,c] * seq[c,l].
__global__ __launch_bounds__(256) void kxz(
    const float* __restrict__ x, const float* __restrict__ wip,
    float* __restrict__ ws, int b0) {
  int bi = blockIdx.y, gb = b0 + bi;
  float* s = ws + (size_t)bi * PER_B;
  int bid = blockIdx.x;
  int h = bid >> 4, w = bid & 15;
  int tid = threadIdx.x;
  __shared__ float xs[64][16];
  for (int i = tid; i < 1024; i += 256) {
    int c = i >> 4, t = i & 15;
    xs[c][t] = x[(size_t)(gb * 64 + c) * NL + t * 256 + h * 16 + w];
  }
  __syncthreads();
  int e = tid;
  float acc[16];
#pragma unroll
  for (int t = 0; t < 16; ++t) acc[t] = 0.f;
  for (int c = 0; c < 64; ++c) {
    float wv = wip[e * 64 + c];
#pragma unroll
    for (int t = 0; t < 16; ++t) acc[t] = fmaf(wv, xs[c][t], acc[t]);
  }
  float4* dst = (float4*)(s + OXZ + (size_t)e * NL + h * 256 + w * 16);
#pragma unroll
  for (int q = 0; q < 4; ++q)
    dst[q] = make_float4(acc[q * 4], acc[q * 4 + 1], acc[q * 4 + 2], acc[q * 4 + 3]);
}

// 2. Fused prep per (bi, 32-l tile): dwconv+silu, x_dbl via MFMA, delta, bct.
__global__ __launch_bounds__(256) void k2prep(
    const float* __restrict__ cwf, const float* __restrict__ cbf,
    const float* __restrict__ xpf, const float* __restrict__ dtwf,
    const float* __restrict__ dtbf,
    const float* __restrict__ cwb, const float* __restrict__ cbb,
    const float* __restrict__ xpb, const float* __restrict__ dtwb,
    const float* __restrict__ dtbb,
    float* __restrict__ ws) {
  int bi = blockIdx.y;
  float* s = ws + (size_t)bi * PER_B;
  int lt = blockIdx.x;
  int l0 = lt * 32;
  int l0b = (127 - lt) * 32;
  int tid = threadIdx.x;

  __shared__ float pool[128 * 40];     // X[128][40] during dwconv; xds after
  __shared__ u16 uct[2][32][136];      // uc transposed bf16, d-contiguous +pad
  float (*X)[40] = (float(*)[40])pool;

  for (int i = tid; i < 128 * 38; i += 256) {
    int d = i / 38, j = i - d * 38;
    int l = l0 - 3 + j;
    X[d][j] = (l >= 0 && l < NL) ? s[OXZ + (size_t)d * NL + l] : 0.f;
  }
  __syncthreads();

  u16* ucfp = (u16*)(s + OUCF);
  u16* ucbp = (u16*)(s + OUCB);
  for (int i = tid; i < 2 * 128 * 32; i += 256) {
    int br = i >> 12, rem = i & 4095;
    int d = rem >> 5, li = rem & 31;
    float a;
    if (br == 0) {
      a = cbf[d];
#pragma unroll
      for (int k = 0; k < 4; ++k) a = fmaf(cwf[d * 4 + k], X[d][li + k], a);
    } else {
      a = cbb[d];
#pragma unroll
      for (int k = 0; k < 4; ++k) a = fmaf(cwb[d * 4 + k], X[d][37 - li - k], a);
    }
    a = siluf_(a);
    u16 ab = f2bf(a);
    uct[br][li][d] = ab;
    int lg = br ? (l0b + li) : (l0 + li);
    (br ? ucbp : ucfp)[(size_t)d * NL + lg] = ab;
  }
  __syncthreads();  // X dead; pool becomes xds [2][40][33]

  // x_dbl via MFMA 16x16x32: D[e 48][l 32] per direction, K=128.
  // Wave w: br = w>>1, ltile = w&1; 3 e-tiles x 4 k-steps = 12 MFMAs.
  float* xds = pool;
  {
    int wid = tid >> 6, lane = tid & 63;
    int br = wid >> 1, lt2 = wid & 1;
    int n16 = lane & 15, kg = lane >> 4;
    const float* xp = br ? xpb : xpf;
    f32x4 acc[3] = {};
#pragma unroll
    for (int ks = 0; ks < 4; ++ks) {
      bf16x8 bfrag = *(const bf16x8*)&uct[br][lt2 * 16 + n16][ks * 32 + kg * 8];
#pragma unroll
      for (int et = 0; et < 3; ++et) {
        int e = et * 16 + n16;
        int ec = (e < 40) ? e : 39;          // clamp addr; rows >=40 discarded
        const float* pa = xp + ec * 128 + ks * 32 + kg * 8;
        float4 a0 = *(const float4*)pa;
        float4 a1 = *(const float4*)(pa + 4);
        bf16x8 af;
        af[0] = (short)f2bf(a0.x); af[1] = (short)f2bf(a0.y);
        af[2] = (short)f2bf(a0.z); af[3] = (short)f2bf(a0.w);
        af[4] = (short)f2bf(a1.x); af[5] = (short)f2bf(a1.y);
        af[6] = (short)f2bf(a1.z); af[7] = (short)f2bf(a1.w);
        acc[et] = __builtin_amdgcn_mfma_f32_16x16x32_bf16(af, bfrag, acc[et], 0, 0, 0);
      }
    }
    // D layout: col = lane&15 (l), row = kg*4 + rg (e within 16-tile)
#pragma unroll
    for (int et = 0; et < 3; ++et) {
#pragma unroll
      for (int rg = 0; rg < 4; ++rg) {
        int e = et * 16 + kg * 4 + rg;
        if (e < 40)
          xds[(br * 40 + e) * 33 + lt2 * 16 + n16] = acc[et][rg];
      }
    }
  }
  __syncthreads();

  u16* dlfp = (u16*)(s + ODLF);
  u16* dlbp = (u16*)(s + ODLB);
  for (int i = tid; i < 2 * 128 * 32; i += 256) {
    int br = i >> 12, rem = i & 4095;
    int d = rem >> 5, li = rem & 31;
    const float* dtw = br ? dtwb : dtwf;
    float pre = (br ? dtbb : dtbf)[d];
#pragma unroll
    for (int r = 0; r < 8; ++r)
      pre = fmaf(dtw[d * 8 + r], xds[(br * 40 + r) * 33 + li], pre);
    int lg = br ? (l0b + li) : (l0 + li);
    (br ? dlbp : dlfp)[(size_t)d * NL + lg] = f2bf(softplusf_(pre));
  }
  u16* bctp = (u16*)(s + OO2);
  for (int i = tid; i < 2 * 32 * 32; i += 256) {
    int dir = i >> 10;
    int li = (i >> 5) & 31, k = i & 31;
    int lg = dir ? (l0b + li) : (l0 + li);
    bctp[((size_t)dir * 4096 + lg) * 32 + k] = f2bf(xds[(dir * 40 + 8 + k) * 33 + li]);
  }
}

// 5a. Phase A: 16 d-rows/block; chunk bct (bf16) staged to fp32 LDS;
// ushort8 dl/uc loads = 8 steps per load pair.
__global__ __launch_bounds__(256) void kscanA(
    const float* __restrict__ Alf, const float* __restrict__ Alb,
    float* __restrict__ ws) {
  int bi = blockIdx.y;
  float* s = ws + (size_t)bi * PER_B;
  int xid = blockIdx.x;
  int chunk = xid >> 4, dir = (xid >> 3) & 1, d8 = xid & 7;
  int tid = threadIdx.x;
  int wv = tid >> 6, lane = tid & 63;
  int n = lane & 15, g = lane >> 4;
  int d = d8 * 16 + wv * 4 + g;
  int l0 = chunk * CL;
  __shared__ float bl[CL * 32];
  {
    const u16* bctp = (const u16*)(s + OO2) + ((size_t)dir * 4096 + l0) * 32;
    for (int i = tid; i < CL * 32; i += 256)
      bl[i] = __uint_as_float(((u32)bctp[i]) << 16);
  }
  __syncthreads();
  const u16* ucp = (const u16*)(s + (dir ? OUCB : OUCF)) + (size_t)d * NL + l0;
  const u16* dlp = (const u16*)(s + (dir ? ODLB : ODLF)) + (size_t)d * NL + l0;
  float A = -__expf((dir ? Alb : Alf)[d * 16 + n]);
  float P = 1.f, S = 0.f;
  for (int i0 = 0; i0 < CL; i0 += 8) {
    uint4 dq = *(const uint4*)(dlp + i0);
    uint4 uq = *(const uint4*)(ucp + i0);
    float dv[8] = {bflo(dq.x), bfhi(dq.x), bflo(dq.y), bfhi(dq.y),
                   bflo(dq.z), bfhi(dq.z), bflo(dq.w), bfhi(dq.w)};
    float uv[8] = {bflo(uq.x), bfhi(uq.x), bflo(uq.y), bfhi(uq.y),
                   bflo(uq.z), bfhi(uq.z), bflo(uq.w), bfhi(uq.w)};
#pragma unroll
    for (int j = 0; j < 8; ++j) {
      float dA = __expf(dv[j] * A);
      S = fmaf(dA, S, dv[j] * bl[(i0 + j) * 32 + n] * uv[j]);
      P *= dA;
    }
  }
  size_t cidx = ((size_t)(chunk * 2 + dir) * 128 + d) * 16 + n;
  s[OO + cidx] = P;
  s[OO + 262144u + cidx] = S;
}

// 5b. Phase B: carry combine.
__global__ __launch_bounds__(64) void kscanB(float* __restrict__ ws) {
  int bi = blockIdx.y;
  float* s = ws + (size_t)bi * PER_B;
  int dir = blockIdx.x >> 5, dblk = blockIdx.x & 31;
  int tid = threadIdx.x;
  size_t base = (size_t)dir * 2048 + dblk * 64 + tid;
  float carry = 0.f;
#pragma unroll 4
  for (int c = 0; c < NCH; ++c) {
    size_t idx = (size_t)c * 4096 + base;
    float pv = s[OO + idx], sv = s[OO + 262144u + idx];
    s[OO + 262144u + idx] = carry;
    carry = fmaf(pv, carry, sv);
  }
}

// 5c. Phase C: seeded re-scan; bf16 inputs; DPP row-sum; ps[16][65] staging.
__global__ __launch_bounds__(256) void kscanC(
    const float* __restrict__ Alf, const float* __restrict__ Df,
    const float* __restrict__ Alb, const float* __restrict__ Db,
    float* __restrict__ ws) {
  int bi = blockIdx.y;
  float* s = ws + (size_t)bi * PER_B;
  int xid = blockIdx.x;
  int chunk = xid >> 4, dir = (xid >> 3) & 1, d8 = xid & 7;
  int tid = threadIdx.x;
  int wv = tid >> 6, lane = tid & 63;
  int n = lane & 15, g = lane >> 4;
  int d = d8 * 16 + wv * 4 + g;
  int l0 = chunk * CL;
  __shared__ float bl[CL * 32];
  __shared__ float ps[16][65];
  {
    const u16* bctp = (const u16*)(s + OO2) + ((size_t)dir * 4096 + l0) * 32;
    for (int i = tid; i < CL * 32; i += 256)
      bl[i] = __uint_as_float(((u32)bctp[i]) << 16);
  }
  __syncthreads();
  const u16* ucp = (const u16*)(s + (dir ? OUCB : OUCF)) + (size_t)d * NL + l0;
  const u16* dlp = (const u16*)(s + (dir ? ODLB : ODLF)) + (size_t)d * NL + l0;
  float* ybase = s + (dir ? OYB : OYF);
  float A = -__expf((dir ? Alb : Alf)[d * 16 + n]);
  float Dv = (dir ? Db : Df)[d];
  size_t cidx = ((size_t)(chunk * 2 + dir) * 128 + d) * 16 + n;
  float h = s[OO + 262144u + cidx];
  int prow = wv * 4 + g;
  for (int i0 = 0; i0 < CL; i0 += 8) {
    uint4 dq = *(const uint4*)(dlp + i0);
    uint4 uq = *(const uint4*)(ucp + i0);
    float dv[8] = {bflo(dq.x), bfhi(dq.x), bflo(dq.y), bfhi(dq.y),
                   bflo(dq.z), bfhi(dq.z), bflo(dq.w), bfhi(dq.w)};
    float uv[8] = {bflo(uq.x), bfhi(uq.x), bflo(uq.y), bfhi(uq.y),
                   bflo(uq.z), bfhi(uq.z), bflo(uq.w), bfhi(uq.w)};
#pragma unroll
    for (int j = 0; j < 8; ++j) {
      int i = i0 + j;
      float dA = __expf(dv[j] * A);
      h = fmaf(dA, h, dv[j] * bl[i * 32 + n] * uv[j]);
      float p = rowsum16_(h * bl[i * 32 + 16 + n]);
      if (n == 0) ps[prow][i] = fmaf(uv[j], Dv, p);
    }
  }
  __syncthreads();
  for (int i = tid; i < 16 * CL; i += 256) {
    int row = i >> 6, col = i & 63;
    ybase[(size_t)(d8 * 16 + row) * NL + l0 + col] = ps[row][col];
  }
}

// 6. Fused gate + out-proj. Block = 32-l tile.
__global__ __launch_bounds__(256) void koutg(
    const float* __restrict__ wout, float* __restrict__ ws) {
  int bi = blockIdx.y;
  float* s = ws + (size_t)bi * PER_B;
  int lt = blockIdx.x;
  int l0 = lt * 32;
  int tid = threadIdx.x;
  __shared__ float ot[128][32];
  __shared__ float ot2[64][33];
  for (int i = tid; i < 128 * 32; i += 256) {
    int d = i >> 5, li = i & 31;
    int l = l0 + li;
    float z = s[OXZ + (size_t)(128 + d) * NL + l];
    float v = s[OYF + (size_t)d * NL + l] + s[OYB + (size_t)d * NL + (NL - 1 - l)];
    ot[d][li] = v * siluf_(z);
  }
  __syncthreads();
  {
    int li = tid & 31, cg = tid >> 5;
    float acc[8];
#pragma unroll
    for (int j = 0; j < 8; ++j) acc[j] = 0.f;
    for (int d4 = 0; d4 < 128; d4 += 4) {
      float o0 = ot[d4][li], o1 = ot[d4 + 1][li];
      float o2v = ot[d4 + 2][li], o3 = ot[d4 + 3][li];
#pragma unroll
      for (int j = 0; j < 8; ++j) {
        float4 w4 = *(const float4*)&wout[(cg * 8 + j) * 128 + d4];
        acc[j] = fmaf(w4.x, o0, fmaf(w4.y, o1, fmaf(w4.z, o2v, fmaf(w4.w, o3, acc[j]))));
      }
    }
#pragma unroll
    for (int j = 0; j < 8; ++j) ot2[cg * 8 + j][li] = acc[j];
  }
  __syncthreads();
  for (int i = tid; i < 32 * 64; i += 256) {
    int li = i >> 6, c = i & 63;
    s[OO2 + (size_t)(l0 + li) * 64 + c] = ot2[c][li];
  }
}

// 6.5. Weight prep: Wbf[27][co 64][ci 64] bf16 into slab0's OO scratch
// (dead after kscanC). 27 blocks, one per tap.
__global__ __launch_bounds__(256) void kprepw(
    const float* __restrict__ pw, float* __restrict__ ws) {
  int off = blockIdx.x;
  u16* wb = (u16*)(ws + OO);
  int tid = threadIdx.x;
  for (int i = tid; i < 4096; i += 256) {
    int co = i >> 6, ci = i & 63;
    wb[off * 4096 + i] = f2bf(pw[(size_t)(co * 64 + ci) * 27 + off]);
  }
}

// 7. conv3d as bf16 implicit GEMM on MFMA (fp32 accum). Block tile
// [64 co][64 l] = one t-plane x 4 h-rows; grid = t(16) x hq(4) = 64/slab.
// LDS: zero-padded halo Xs[tt 3][hh 6][ww 18][ci 64 pad 72] bf16 (46.6 KB),
// ci-contiguous so B-frags are single ds_read_b128 of 8 ci.
// Wave (of 4) = [32 co][32 l]; per K-step: 2 A global 16B loads (Wbf, L1/L2
// resident) + 2 ds_read_b128 + 4 mfma_f32_16x16x32_bf16. 54 K-steps.
// Writes FINAL conv + bias + residual to OX4.
__global__ __launch_bounds__(256) void kconv3(
    const float* __restrict__ pb, const float* __restrict__ xin,
    float* __restrict__ ws, int b0) {
  int bi = blockIdx.y, gb = b0 + bi;
  float* s = ws + (size_t)bi * PER_B;
  int t = blockIdx.x >> 2, hq = blockIdx.x & 3;
  int h0 = hq * 4;
  int tid = threadIdx.x;
  const u16* wb = (const u16*)(ws + OO);  // slab0 weights (shared)
  const float* xr = s + OO2;              // o2 in c'-major view [64][4096]

  __shared__ u16 Xs[3 * 6 * 18 * 72];
  // zero (covers t/h/w halo padding)
  {
    u32* xz32 = (u32*)Xs;
    for (int i = tid; i < 3 * 6 * 18 * 72 / 2; i += 256) xz32[i] = 0u;
  }
  __syncthreads();
  // stage valid rows, transposed to ci-contiguous bf16
  {
    int ci = tid >> 2, wq = tid & 3;
    for (int row = 0; row < 18; ++row) {
      int tt = row / 6, hh = row - tt * 6;
      int ts = t + tt - 1, hs = h0 + hh - 1;
      if (ts < 0 || ts > 15 || hs < 0 || hs > 15) continue;
      float4 v = *(const float4*)(xr + (size_t)ci * NL + ts * 256 + hs * 16 + wq * 4);
      int rb = (tt * 6 + hh) * 18 + 1 + wq * 4;
      Xs[(rb + 0) * 72 + ci] = f2bf(v.x);
      Xs[(rb + 1) * 72 + ci] = f2bf(v.y);
      Xs[(rb + 2) * 72 + ci] = f2bf(v.z);
      Xs[(rb + 3) * 72 + ci] = f2bf(v.w);
    }
  }
  __syncthreads();

  int wid = tid >> 6, lane = tid & 63;
  int cb = wid >> 1, lb = wid & 1;
  int n16 = lane & 15, kg = lane >> 4;   // k-group 0..3 (8 ci each)
  f32x4 acc[2][2] = {};                  // [c2 co-subtile][l2 l-subtile]

  // A: Wbf[off][co][ci]; lane row co = cb*32 + c2*16 + n16, k = kg*8+st*32+j
  const u16* wbA = wb + (size_t)(cb * 32 + n16) * 64 + kg * 8;
  for (int kt = 0; kt < 3; ++kt)
    for (int kh = 0; kh < 3; ++kh) {
      int rbase = (kt * 6 + lb * 2 + kh) * 18 + n16;
#pragma unroll
      for (int kw = 0; kw < 3; ++kw) {
        int off = (kt * 3 + kh) * 3 + kw;
        int r0 = rbase + kw;       // l2=0 spatial row
        const u16* pa = wbA + off * 4096;
#pragma unroll
        for (int st = 0; st < 2; ++st) {
          int kb = st * 32;
          bf16x8 a0 = *(const bf16x8*)(pa + kb);
          bf16x8 a1 = *(const bf16x8*)(pa + 16 * 64 + kb);
          bf16x8 b0 = *(const bf16x8*)(&Xs[r0 * 72 + kb + kg * 8]);
          bf16x8 b1 = *(const bf16x8*)(&Xs[(r0 + 18) * 72 + kb + kg * 8]);
          acc[0][0] = __builtin_amdgcn_mfma_f32_16x16x32_bf16(a0, b0, acc[0][0], 0, 0, 0);
          acc[0][1] = __builtin_amdgcn_mfma_f32_16x16x32_bf16(a0, b1, acc[0][1], 0, 0, 0);
          acc[1][0] = __builtin_amdgcn_mfma_f32_16x16x32_bf16(a1, b0, acc[1][0], 0, 0, 0);
          acc[1][1] = __builtin_amdgcn_mfma_f32_16x16x32_bf16(a1, b1, acc[1][1], 0, 0, 0);
        }
      }
    }

  // C/D layout: col = lane&15 (w), row = kg*4 + reg (co within 16-subtile)
#pragma unroll
  for (int c2 = 0; c2 < 2; ++c2) {
#pragma unroll
    for (int l2 = 0; l2 < 2; ++l2) {
      int lg = t * 256 + (h0 + lb * 2 + l2) * 16 + n16;
#pragma unroll
      for (int rg = 0; rg < 4; ++rg) {
        int co = cb * 32 + c2 * 16 + kg * 4 + rg;
        float v = acc[c2][l2][rg] + pb[co] +
                  xin[(size_t)(gb * 64 + co) * NL + lg];
        s[OX4 + (size_t)co * NL + lg] = v;
      }
    }
  }
}

// 8. knorm: LDS-tiled 1x1x1 mix over the single conv3 output + norm_b.
__global__ __launch_bounds__(256) void knorm(
    const float* __restrict__ nw, const float* __restrict__ nb,
    float* __restrict__ out, float* __restrict__ ws, int b0) {
  int bi = blockIdx.y, gb = b0 + bi;
  float* s = ws + (size_t)bi * PER_B;
  int pt = blockIdx.x;
  int p0 = pt * 64;
  int tid = threadIdx.x;
  __shared__ float xs[64][64];
  for (int i = tid; i < 4096; i += 256) {
    int ci = i >> 6, p = i & 63;
    xs[ci][p] = s[OX4 + (size_t)ci * NL + p0 + p];
  }
  __syncthreads();
  int co = tid >> 2, pq = tid & 3;
  float acc[16];
#pragma unroll
  for (int j = 0; j < 16; ++j) acc[j] = 0.f;
  for (int ci = 0; ci < 64; ci += 4) {
    float4 w4 = *(const float4*)&nw[co * 64 + ci];
    float wv[4] = {w4.x, w4.y, w4.z, w4.w};
#pragma unroll
    for (int cc = 0; cc < 4; ++cc) {
      const float4* row = (const float4*)&xs[ci + cc][pq * 16];
      float4 a = row[0], b = row[1], c = row[2], e = row[3];
      acc[0] = fmaf(wv[cc], a.x, acc[0]);  acc[1] = fmaf(wv[cc], a.y, acc[1]);
      acc[2] = fmaf(wv[cc], a.z, acc[2]);  acc[3] = fmaf(wv[cc], a.w, acc[3]);
      acc[4] = fmaf(wv[cc], b.x, acc[4]);  acc[5] = fmaf(wv[cc], b.y, acc[5]);
      acc[6] = fmaf(wv[cc], b.z, acc[6]);  acc[7] = fmaf(wv[cc], b.w, acc[7]);
      acc[8] = fmaf(wv[cc], c.x, acc[8]);  acc[9] = fmaf(wv[cc], c.y, acc[9]);
      acc[10] = fmaf(wv[cc], c.z, acc[10]); acc[11] = fmaf(wv[cc], c.w, acc[11]);
      acc[12] = fmaf(wv[cc], e.x, acc[12]); acc[13] = fmaf(wv[cc], e.y, acc[13]);
      acc[14] = fmaf(wv[cc], e.z, acc[14]); acc[15] = fmaf(wv[cc], e.w, acc[15]);
    }
  }
  float bias = nb[co];
  float4* dst = (float4*)(out + (size_t)(gb * 64 + co) * NL + p0 + pq * 16);
#pragma unroll
  for (int q = 0; q < 4; ++q)
    dst[q] = make_float4(acc[q * 4] + bias, acc[q * 4 + 1] + bias,
                         acc[q * 4 + 2] + bias, acc[q * 4 + 3] + bias);
}

// ---------------------------------------------------------------------------
extern "C" void kernel_launch(void* const* d_in, const int* in_sizes, int n_in,
                              void* d_out, int out_size, void* d_ws, size_t ws_size,
                              hipStream_t stream) {
  const float* x    = (const float*)d_in[0];
  const float* wip  = (const float*)d_in[1];
  const float* cwf  = (const float*)d_in[2];
  const float* cbf  = (const float*)d_in[3];
  const float* xpf  = (const float*)d_in[4];
  const float* dtwf = (const float*)d_in[5];
  const float* dtbf = (const float*)d_in[6];
  const float* Alf  = (const float*)d_in[7];
  const float* Df   = (const float*)d_in[8];
  const float* cwb  = (const float*)d_in[9];
  const float* cbb  = (const float*)d_in[10];
  const float* xpb  = (const float*)d_in[11];
  const float* dtwb = (const float*)d_in[12];
  const float* dtbb = (const float*)d_in[13];
  const float* Alb  = (const float*)d_in[14];
  const float* Db   = (const float*)d_in[15];
  const float* wout = (const float*)d_in[16];
  const float* pw   = (const float*)d_in[17];
  const float* pb   = (const float*)d_in[18];
  const float* nw   = (const float*)d_in[19];
  const float* nb   = (const float*)d_in[20];

  const size_t PER_B_BYTES = (size_t)PER_B * 4;  // 22,282,240 per batch slab
  int bcnt;
  if (ws_size >= 4 * PER_B_BYTES) bcnt = 4;
  else if (ws_size >= PER_B_BYTES) bcnt = 1;
  else return;
  int passes = 4 / bcnt;

  float* ws = (float*)d_ws;
  for (int p = 0; p < passes; ++p) {
    int b0 = p * bcnt;
    kxz   <<<dim3(256, bcnt), 256, 0, stream>>>(x, wip, ws, b0);
    k2prep<<<dim3(128, bcnt), 256, 0, stream>>>(cwf, cbf, xpf, dtwf, dtbf,
                                                cwb, cbb, xpb, dtwb, dtbb, ws);
    kscanA<<<dim3(1024, bcnt), 256, 0, stream>>>(Alf, Alb, ws);
    kscanB<<<dim3(64, bcnt), 64, 0, stream>>>(ws);
    kscanC<<<dim3(1024, bcnt), 256, 0, stream>>>(Alf, Df, Alb, Db, ws);
    koutg <<<dim3(128, bcnt), 256, 0, stream>>>(wout, ws);
    kprepw<<<dim3(27), 256, 0, stream>>>(pw, ws);
    kconv3<<<dim3(64, bcnt), 256, 0, stream>>>(pb, x, ws, b0);
    knorm <<<dim3(64, bcnt), 256, 0, stream>>>(nw, nb, (float*)d_out, ws, b0);
  }
}

// Round 3
// 267.833 us; speedup vs baseline: 1.2016x; 1.0642x over previous
//
#include <hip/hip_runtime.h>

// ---------------------------------------------------------------------------
// Bidirectional Mamba block, MI355X. Round 23:
//  - k2prep: R22 post-mortem showed it latency-bound at 2 blocks/CU (occ 19.5%),
//    not phase-arithmetic-bound. Split fwd/bwd direction into blockIdx.x:
//    grid 512->1024 (4 blocks/CU), LDS 38->29KB, per-block work halved.
//  - softplus: library log1pf (~40 inst) -> __logf(1+exp) (2 trans inst);
//    silu: IEEE div -> v_rcp. Error ~1ulp / ~1e-6 absolute, invisible at bf16.
//  - kconv3 + x_dbl: bf16 implicit-GEMM on MFMA (R21/R22, verified).
// Shapes: B=4, C=64, D=128, L=4096 (l = h*256 + w*16 + t), N=16, R=8.
// ---------------------------------------------------------------------------

#define NL 4096

typedef unsigned short u16;
typedef unsigned int u32;
typedef __attribute__((ext_vector_type(8))) short bf16x8;
typedef __attribute__((ext_vector_type(4))) float f32x4;

__device__ __forceinline__ float siluf_(float x) {
  return x * __builtin_amdgcn_rcpf(1.f + __expf(-x));
}
__device__ __forceinline__ float softplusf_(float x) {
  return (x > 20.f) ? x : __logf(1.f + __expf(x));
}
__device__ __forceinline__ u16 f2bf(float f) {
  u32 u = __float_as_uint(f);
  u += 0x7fffu + ((u >> 16) & 1u);
  return (u16)(u >> 16);
}
__device__ __forceinline__ float bflo(u32 v) { return __uint_as_float(v << 16); }
__device__ __forceinline__ float bfhi(u32 v) { return __uint_as_float(v & 0xFFFF0000u); }

// Sum over the 16-lane DPP row via rotations 1,2,4,8 (VALU pipe, no DS).
__device__ __forceinline__ float rowsum16_(float p) {
  int q;
  q = __builtin_amdgcn_mov_dpp(__float_as_int(p), 0x121, 0xf, 0xf, false);
  p += __int_as_float(q);
  q = __builtin_amdgcn_mov_dpp(__float_as_int(p), 0x122, 0xf, 0xf, false);
  p += __int_as_float(q);
  q = __builtin_amdgcn_mov_dpp(__float_as_int(p), 0x124, 0xf, 0xf, false);
  p += __int_as_float(q);
  q = __builtin_amdgcn_mov_dpp(__float_as_int(p), 0x128, 0xf, 0xf, false);
  p += __int_as_float(q);
  return p;
}

// Per-b slab offsets (fp32 elements; bf16 regions use u16 views at same base)
#define OXZ  0u          // xz [256][4096] fp32
#define OUCF 1048576u    // ucf [128][4096] bf16 (u16 view)
#define OUCB 1572864u    // ucb [128][4096] bf16 (flipped coords)
#define ODLF 2424832u    // dlf [128][4096] bf16
#define ODLB 2949120u    // dlb [128][4096] bf16 (flipped coords)
#define OYF  3473408u    // yf [128][4096] fp32
#define OYB  3997696u    // yb [128][4096] fp32 (flipped coords)
#define OO   4521984u    // scan scratch P/S; after kscanC: slab0 holds Wbf bf16
#define OO2  5046272u    // bct bf16 until kscanC; then o2 [4096][64] fp32
#define OX4  5308416u    // conv3 final output (+bias+residual)
#define PER_B 5570560u

#define NCH 64   // scan chunks
#define CL  64   // chunk length

// 1. xz[e,l] = sum_c in_proj_w[e,c] * seq[c,l].
__global__ __launch_bounds__(256) void kxz(
    const float* __restrict__ x, const float* __restrict__ wip,
    float* __restrict__ ws, int b0) {
  int bi = blockIdx.y, gb = b0 + bi;
  float* s = ws + (size_t)bi * PER_B;
  int bid = blockIdx.x;
  int h = bid >> 4, w = bid & 15;
  int tid = threadIdx.x;
  __shared__ float xs[64][16];
  for (int i = tid; i < 1024; i += 256) {
    int c = i >> 4, t = i & 15;
    xs[c][t] = x[(size_t)(gb * 64 + c) * NL + t * 256 + h * 16 + w];
  }
  __syncthreads();
  int e = tid;
  float acc[16];
#pragma unroll
  for (int t = 0; t < 16; ++t) acc[t] = 0.f;
  for (int c = 0; c < 64; ++c) {
    float wv = wip[e * 64 + c];
#pragma unroll
    for (int t = 0; t < 16; ++t) acc[t] = fmaf(wv, xs[c][t], acc[t]);
  }
  float4* dst = (float4*)(s + OXZ + (size_t)e * NL + h * 256 + w * 16);
#pragma unroll
  for (int q = 0; q < 4; ++q)
    dst[q] = make_float4(acc[q * 4], acc[q * 4 + 1], acc[q * 4 + 2], acc[q * 4 + 3]);
}

// 2. Fused prep per (bi, dir, 32-l tile): dwconv+silu, x_dbl via MFMA, delta,
// bct. Grid x = 256 (lt 128 x dir 2) -> 1024 blocks total, 4/CU.
__global__ __launch_bounds__(256) void k2prep(
    const float* __restrict__ cwf, const float* __restrict__ cbf,
    const float* __restrict__ xpf, const float* __restrict__ dtwf,
    const float* __restrict__ dtbf,
    const float* __restrict__ cwb, const float* __restrict__ cbb,
    const float* __restrict__ xpb, const float* __restrict__ dtwb,
    const float* __restrict__ dtbb,
    float* __restrict__ ws) {
  int bi = blockIdx.y;
  float* s = ws + (size_t)bi * PER_B;
  int bx = blockIdx.x;
  int lt = bx >> 1, dir = bx & 1;
  int l0 = lt * 32;
  int lout0 = dir ? (127 - lt) * 32 : l0;   // output base (flipped for bwd)
  int tid = threadIdx.x;

  __shared__ float pool[128 * 40];   // X[128][40] during dwconv; xds after
  __shared__ u16 uct[32][136];       // uc transposed bf16 (d-contig, 16B rows)
  float (*X)[40] = (float(*)[40])pool;

  for (int i = tid; i < 128 * 38; i += 256) {
    int d = i / 38, j = i - d * 38;
    int l = l0 - 3 + j;
    X[d][j] = (l >= 0 && l < NL) ? s[OXZ + (size_t)d * NL + l] : 0.f;
  }
  __syncthreads();

  const float* cw = dir ? cwb : cwf;
  const float* cb = dir ? cbb : cbf;
  u16* ucg = (u16*)(s + (dir ? OUCB : OUCF));
  for (int i = tid; i < 128 * 32; i += 256) {
    int d = i >> 5, li = i & 31;
    float a = cb[d];
    if (dir == 0) {
#pragma unroll
      for (int k = 0; k < 4; ++k) a = fmaf(cw[d * 4 + k], X[d][li + k], a);
    } else {
#pragma unroll
      for (int k = 0; k < 4; ++k) a = fmaf(cw[d * 4 + k], X[d][37 - li - k], a);
    }
    a = siluf_(a);
    u16 ab = f2bf(a);
    uct[li][d] = ab;
    ucg[(size_t)d * NL + lout0 + li] = ab;
  }
  __syncthreads();  // X dead; pool becomes xds [40][33]

  // x_dbl via MFMA 16x16x32: D[e 48][l 32], K=128. Units (et,lt2) = 6 over
  // 4 waves (waves 0,1 take two units).
  float* xds = pool;
  {
    int wid = tid >> 6, lane = tid & 63;
    int n16 = lane & 15, kg = lane >> 4;
    const float* xp = dir ? xpb : xpf;
#pragma unroll
    for (int rep = 0; rep < 2; ++rep) {
      int id = wid + rep * 4;
      if (id < 6) {
        int et = id >> 1, lt2 = id & 1;
        f32x4 acc = {};
#pragma unroll
        for (int ks = 0; ks < 4; ++ks) {
          bf16x8 bfrag = *(const bf16x8*)&uct[lt2 * 16 + n16][ks * 32 + kg * 8];
          int e = et * 16 + n16;
          int ec = (e < 40) ? e : 39;        // clamp addr; rows >=40 discarded
          const float* pa = xp + ec * 128 + ks * 32 + kg * 8;
          float4 a0 = *(const float4*)pa;
          float4 a1 = *(const float4*)(pa + 4);
          bf16x8 af;
          af[0] = (short)f2bf(a0.x); af[1] = (short)f2bf(a0.y);
          af[2] = (short)f2bf(a0.z); af[3] = (short)f2bf(a0.w);
          af[4] = (short)f2bf(a1.x); af[5] = (short)f2bf(a1.y);
          af[6] = (short)f2bf(a1.z); af[7] = (short)f2bf(a1.w);
          acc = __builtin_amdgcn_mfma_f32_16x16x32_bf16(af, bfrag, acc, 0, 0, 0);
        }
        // D layout: col = lane&15 (l), row = kg*4 + rg (e within 16-tile)
#pragma unroll
        for (int rg = 0; rg < 4; ++rg) {
          int e = et * 16 + kg * 4 + rg;
          if (e < 40) xds[e * 33 + lt2 * 16 + n16] = acc[rg];
        }
      }
    }
  }
  __syncthreads();

  const float* dtw = dir ? dtwb : dtwf;
  const float* dtb = dir ? dtbb : dtbf;
  u16* dlg = (u16*)(s + (dir ? ODLB : ODLF));
  for (int i = tid; i < 128 * 32; i += 256) {
    int d = i >> 5, li = i & 31;
    float pre = dtb[d];
#pragma unroll
    for (int r = 0; r < 8; ++r)
      pre = fmaf(dtw[d * 8 + r], xds[r * 33 + li], pre);
    dlg[(size_t)d * NL + lout0 + li] = f2bf(softplusf_(pre));
  }
  u16* bctp = (u16*)(s + OO2);
  for (int i = tid; i < 32 * 32; i += 256) {
    int li = i >> 5, k = i & 31;
    bctp[((size_t)dir * 4096 + lout0 + li) * 32 + k] = f2bf(xds[(8 + k) * 33 + li]);
  }
}

// 5a. Phase A: 16 d-rows/block; chunk bct (bf16) staged to fp32 LDS;
// ushort8 dl/uc loads = 8 steps per load pair.
__global__ __launch_bounds__(256) void kscanA(
    const float* __restrict__ Alf, const float* __restrict__ Alb,
    float* __restrict__ ws) {
  int bi = blockIdx.y;
  float* s = ws + (size_t)bi * PER_B;
  int xid = blockIdx.x;
  int chunk = xid >> 4, dir = (xid >> 3) & 1, d8 = xid & 7;
  int tid = threadIdx.x;
  int wv = tid >> 6, lane = tid & 63;
  int n = lane & 15, g = lane >> 4;
  int d = d8 * 16 + wv * 4 + g;
  int l0 = chunk * CL;
  __shared__ float bl[CL * 32];
  {
    const u16* bctp = (const u16*)(s + OO2) + ((size_t)dir * 4096 + l0) * 32;
    for (int i = tid; i < CL * 32; i += 256)
      bl[i] = __uint_as_float(((u32)bctp[i]) << 16);
  }
  __syncthreads();
  const u16* ucp = (const u16*)(s + (dir ? OUCB : OUCF)) + (size_t)d * NL + l0;
  const u16* dlp = (const u16*)(s + (dir ? ODLB : ODLF)) + (size_t)d * NL + l0;
  float A = -__expf((dir ? Alb : Alf)[d * 16 + n]);
  float P = 1.f, S = 0.f;
  for (int i0 = 0; i0 < CL; i0 += 8) {
    uint4 dq = *(const uint4*)(dlp + i0);
    uint4 uq = *(const uint4*)(ucp + i0);
    float dv[8] = {bflo(dq.x), bfhi(dq.x), bflo(dq.y), bfhi(dq.y),
                   bflo(dq.z), bfhi(dq.z), bflo(dq.w), bfhi(dq.w)};
    float uv[8] = {bflo(uq.x), bfhi(uq.x), bflo(uq.y), bfhi(uq.y),
                   bflo(uq.z), bfhi(uq.z), bflo(uq.w), bfhi(uq.w)};
#pragma unroll
    for (int j = 0; j < 8; ++j) {
      float dA = __expf(dv[j] * A);
      S = fmaf(dA, S, dv[j] * bl[(i0 + j) * 32 + n] * uv[j]);
      P *= dA;
    }
  }
  size_t cidx = ((size_t)(chunk * 2 + dir) * 128 + d) * 16 + n;
  s[OO + cidx] = P;
  s[OO + 262144u + cidx] = S;
}

// 5b. Phase B: carry combine.
__global__ __launch_bounds__(64) void kscanB(float* __restrict__ ws) {
  int bi = blockIdx.y;
  float* s = ws + (size_t)bi * PER_B;
  int dir = blockIdx.x >> 5, dblk = blockIdx.x & 31;
  int tid = threadIdx.x;
  size_t base = (size_t)dir * 2048 + dblk * 64 + tid;
  float carry = 0.f;
#pragma unroll 4
  for (int c = 0; c < NCH; ++c) {
    size_t idx = (size_t)c * 4096 + base;
    float pv = s[OO + idx], sv = s[OO + 262144u + idx];
    s[OO + 262144u + idx] = carry;
    carry = fmaf(pv, carry, sv);
  }
}

// 5c. Phase C: seeded re-scan; bf16 inputs; DPP row-sum; ps[16][65] staging.
__global__ __launch_bounds__(256) void kscanC(
    const float* __restrict__ Alf, const float* __restrict__ Df,
    const float* __restrict__ Alb, const float* __restrict__ Db,
    float* __restrict__ ws) {
  int bi = blockIdx.y;
  float* s = ws + (size_t)bi * PER_B;
  int xid = blockIdx.x;
  int chunk = xid >> 4, dir = (xid >> 3) & 1, d8 = xid & 7;
  int tid = threadIdx.x;
  int wv = tid >> 6, lane = tid & 63;
  int n = lane & 15, g = lane >> 4;
  int d = d8 * 16 + wv * 4 + g;
  int l0 = chunk * CL;
  __shared__ float bl[CL * 32];
  __shared__ float ps[16][65];
  {
    const u16* bctp = (const u16*)(s + OO2) + ((size_t)dir * 4096 + l0) * 32;
    for (int i = tid; i < CL * 32; i += 256)
      bl[i] = __uint_as_float(((u32)bctp[i]) << 16);
  }
  __syncthreads();
  const u16* ucp = (const u16*)(s + (dir ? OUCB : OUCF)) + (size_t)d * NL + l0;
  const u16* dlp = (const u16*)(s + (dir ? ODLB : ODLF)) + (size_t)d * NL + l0;
  float* ybase = s + (dir ? OYB : OYF);
  float A = -__expf((dir ? Alb : Alf)[d * 16 + n]);
  float Dv = (dir ? Db : Df)[d];
  size_t cidx = ((size_t)(chunk * 2 + dir) * 128 + d) * 16 + n;
  float h = s[OO + 262144u + cidx];
  int prow = wv * 4 + g;
  for (int i0 = 0; i0 < CL; i0 += 8) {
    uint4 dq = *(const uint4*)(dlp + i0);
    uint4 uq = *(const uint4*)(ucp + i0);
    float dv[8] = {bflo(dq.x), bfhi(dq.x), bflo(dq.y), bfhi(dq.y),
                   bflo(dq.z), bfhi(dq.z), bflo(dq.w), bfhi(dq.w)};
    float uv[8] = {bflo(uq.x), bfhi(uq.x), bflo(uq.y), bfhi(uq.y),
                   bflo(uq.z), bfhi(uq.z), bflo(uq.w), bfhi(uq.w)};
#pragma unroll
    for (int j = 0; j < 8; ++j) {
      int i = i0 + j;
      float dA = __expf(dv[j] * A);
      h = fmaf(dA, h, dv[j] * bl[i * 32 + n] * uv[j]);
      float p = rowsum16_(h * bl[i * 32 + 16 + n]);
      if (n == 0) ps[prow][i] = fmaf(uv[j], Dv, p);
    }
  }
  __syncthreads();
  for (int i = tid; i < 16 * CL; i += 256) {
    int row = i >> 6, col = i & 63;
    ybase[(size_t)(d8 * 16 + row) * NL + l0 + col] = ps[row][col];
  }
}

// 6. Fused gate + out-proj. Block = 32-l tile.
__global__ __launch_bounds__(256) void koutg(
    const float* __restrict__ wout, float* __restrict__ ws) {
  int bi = blockIdx.y;
  float* s = ws + (size_t)bi * PER_B;
  int lt = blockIdx.x;
  int l0 = lt * 32;
  int tid = threadIdx.x;
  __shared__ float ot[128][32];
  __shared__ float ot2[64][33];
  for (int i = tid; i < 128 * 32; i += 256) {
    int d = i >> 5, li = i & 31;
    int l = l0 + li;
    float z = s[OXZ + (size_t)(128 + d) * NL + l];
    float v = s[OYF + (size_t)d * NL + l] + s[OYB + (size_t)d * NL + (NL - 1 - l)];
    ot[d][li] = v * siluf_(z);
  }
  __syncthreads();
  {
    int li = tid & 31, cg = tid >> 5;
    float acc[8];
#pragma unroll
    for (int j = 0; j < 8; ++j) acc[j] = 0.f;
    for (int d4 = 0; d4 < 128; d4 += 4) {
      float o0 = ot[d4][li], o1 = ot[d4 + 1][li];
      float o2v = ot[d4 + 2][li], o3 = ot[d4 + 3][li];
#pragma unroll
      for (int j = 0; j < 8; ++j) {
        float4 w4 = *(const float4*)&wout[(cg * 8 + j) * 128 + d4];
        acc[j] = fmaf(w4.x, o0, fmaf(w4.y, o1, fmaf(w4.z, o2v, fmaf(w4.w, o3, acc[j]))));
      }
    }
#pragma unroll
    for (int j = 0; j < 8; ++j) ot2[cg * 8 + j][li] = acc[j];
  }
  __syncthreads();
  for (int i = tid; i < 32 * 64; i += 256) {
    int li = i >> 6, c = i & 63;
    s[OO2 + (size_t)(l0 + li) * 64 + c] = ot2[c][li];
  }
}

// 6.5. Weight prep: Wbf[27][co 64][ci 64] bf16 into slab0's OO scratch
// (dead after kscanC). 27 blocks, one per tap.
__global__ __launch_bounds__(256) void kprepw(
    const float* __restrict__ pw, float* __restrict__ ws) {
  int off = blockIdx.x;
  u16* wb = (u16*)(ws + OO);
  int tid = threadIdx.x;
  for (int i = tid; i < 4096; i += 256) {
    int co = i >> 6, ci = i & 63;
    wb[off * 4096 + i] = f2bf(pw[(size_t)(co * 64 + ci) * 27 + off]);
  }
}

// 7. conv3d as bf16 implicit GEMM on MFMA (fp32 accum). Block tile
// [64 co][64 l] = one t-plane x 4 h-rows; grid = t(16) x hq(4) = 64/slab.
// LDS: zero-padded halo Xs[tt 3][hh 6][ww 18][ci 64 pad 72] bf16 (46.6 KB),
// ci-contiguous so B-frags are single ds_read_b128 of 8 ci.
// Wave (of 4) = [32 co][32 l]; per K-step: 2 A global 16B loads (Wbf, L1/L2
// resident) + 2 ds_read_b128 + 4 mfma_f32_16x16x32_bf16. 54 K-steps.
// Writes FINAL conv + bias + residual to OX4.
__global__ __launch_bounds__(256) void kconv3(
    const float* __restrict__ pb, const float* __restrict__ xin,
    float* __restrict__ ws, int b0) {
  int bi = blockIdx.y, gb = b0 + bi;
  float* s = ws + (size_t)bi * PER_B;
  int t = blockIdx.x >> 2, hq = blockIdx.x & 3;
  int h0 = hq * 4;
  int tid = threadIdx.x;
  const u16* wb = (const u16*)(ws + OO);  // slab0 weights (shared)
  const float* xr = s + OO2;              // o2 in c'-major view [64][4096]

  __shared__ u16 Xs[3 * 6 * 18 * 72];
  // zero (covers t/h/w halo padding)
  {
    u32* xz32 = (u32*)Xs;
    for (int i = tid; i < 3 * 6 * 18 * 72 / 2; i += 256) xz32[i] = 0u;
  }
  __syncthreads();
  // stage valid rows, transposed to ci-contiguous bf16
  {
    int ci = tid >> 2, wq = tid & 3;
    for (int row = 0; row < 18; ++row) {
      int tt = row / 6, hh = row - tt * 6;
      int ts = t + tt - 1, hs = h0 + hh - 1;
      if (ts < 0 || ts > 15 || hs < 0 || hs > 15) continue;
      float4 v = *(const float4*)(xr + (size_t)ci * NL + ts * 256 + hs * 16 + wq * 4);
      int rb = (tt * 6 + hh) * 18 + 1 + wq * 4;
      Xs[(rb + 0) * 72 + ci] = f2bf(v.x);
      Xs[(rb + 1) * 72 + ci] = f2bf(v.y);
      Xs[(rb + 2) * 72 + ci] = f2bf(v.z);
      Xs[(rb + 3) * 72 + ci] = f2bf(v.w);
    }
  }
  __syncthreads();

  int wid = tid >> 6, lane = tid & 63;
  int cb = wid >> 1, lb = wid & 1;
  int n16 = lane & 15, kg = lane >> 4;   // k-group 0..3 (8 ci each)
  f32x4 acc[2][2] = {};                  // [c2 co-subtile][l2 l-subtile]

  // A: Wbf[off][co][ci]; lane row co = cb*32 + c2*16 + n16, k = kg*8+st*32+j
  const u16* wbA = wb + (size_t)(cb * 32 + n16) * 64 + kg * 8;
  for (int kt = 0; kt < 3; ++kt)
    for (int kh = 0; kh < 3; ++kh) {
      int rbase = (kt * 6 + lb * 2 + kh) * 18 + n16;
#pragma unroll
      for (int kw = 0; kw < 3; ++kw) {
        int off = (kt * 3 + kh) * 3 + kw;
        int r0 = rbase + kw;       // l2=0 spatial row
        const u16* pa = wbA + off * 4096;
#pragma unroll
        for (int st = 0; st < 2; ++st) {
          int kb = st * 32;
          bf16x8 a0 = *(const bf16x8*)(pa + kb);
          bf16x8 a1 = *(const bf16x8*)(pa + 16 * 64 + kb);
          bf16x8 b0 = *(const bf16x8*)(&Xs[r0 * 72 + kb + kg * 8]);
          bf16x8 b1 = *(const bf16x8*)(&Xs[(r0 + 18) * 72 + kb + kg * 8]);
          acc[0][0] = __builtin_amdgcn_mfma_f32_16x16x32_bf16(a0, b0, acc[0][0], 0, 0, 0);
          acc[0][1] = __builtin_amdgcn_mfma_f32_16x16x32_bf16(a0, b1, acc[0][1], 0, 0, 0);
          acc[1][0] = __builtin_amdgcn_mfma_f32_16x16x32_bf16(a1, b0, acc[1][0], 0, 0, 0);
          acc[1][1] = __builtin_amdgcn_mfma_f32_16x16x32_bf16(a1, b1, acc[1][1], 0, 0, 0);
        }
      }
    }

  // C/D layout: col = lane&15 (w), row = kg*4 + reg (co within 16-subtile)
#pragma unroll
  for (int c2 = 0; c2 < 2; ++c2) {
#pragma unroll
    for (int l2 = 0; l2 < 2; ++l2) {
      int lg = t * 256 + (h0 + lb * 2 + l2) * 16 + n16;
#pragma unroll
      for (int rg = 0; rg < 4; ++rg) {
        int co = cb * 32 + c2 * 16 + kg * 4 + rg;
        float v = acc[c2][l2][rg] + pb[co] +
                  xin[(size_t)(gb * 64 + co) * NL + lg];
        s[OX4 + (size_t)co * NL + lg] = v;
      }
    }
  }
}

// 8. knorm: LDS-tiled 1x1x1 mix over the single conv3 output + norm_b.
__global__ __launch_bounds__(256) void knorm(
    const float* __restrict__ nw, const float* __restrict__ nb,
    float* __restrict__ out, float* __restrict__ ws, int b0) {
  int bi = blockIdx.y, gb = b0 + bi;
  float* s = ws + (size_t)bi * PER_B;
  int pt = blockIdx.x;
  int p0 = pt * 64;
  int tid = threadIdx.x;
  __shared__ float xs[64][64];
  for (int i = tid; i < 4096; i += 256) {
    int ci = i >> 6, p = i & 63;
    xs[ci][p] = s[OX4 + (size_t)ci * NL + p0 + p];
  }
  __syncthreads();
  int co = tid >> 2, pq = tid & 3;
  float acc[16];
#pragma unroll
  for (int j = 0; j < 16; ++j) acc[j] = 0.f;
  for (int ci = 0; ci < 64; ci += 4) {
    float4 w4 = *(const float4*)&nw[co * 64 + ci];
    float wv[4] = {w4.x, w4.y, w4.z, w4.w};
#pragma unroll
    for (int cc = 0; cc < 4; ++cc) {
      const float4* row = (const float4*)&xs[ci + cc][pq * 16];
      float4 a = row[0], b = row[1], c = row[2], e = row[3];
      acc[0] = fmaf(wv[cc], a.x, acc[0]);  acc[1] = fmaf(wv[cc], a.y, acc[1]);
      acc[2] = fmaf(wv[cc], a.z, acc[2]);  acc[3] = fmaf(wv[cc], a.w, acc[3]);
      acc[4] = fmaf(wv[cc], b.x, acc[4]);  acc[5] = fmaf(wv[cc], b.y, acc[5]);
      acc[6] = fmaf(wv[cc], b.z, acc[6]);  acc[7] = fmaf(wv[cc], b.w, acc[7]);
      acc[8] = fmaf(wv[cc], c.x, acc[8]);  acc[9] = fmaf(wv[cc], c.y, acc[9]);
      acc[10] = fmaf(wv[cc], c.z, acc[10]); acc[11] = fmaf(wv[cc], c.w, acc[11]);
      acc[12] = fmaf(wv[cc], e.x, acc[12]); acc[13] = fmaf(wv[cc], e.y, acc[13]);
      acc[14] = fmaf(wv[cc], e.z, acc[14]); acc[15] = fmaf(wv[cc], e.w, acc[15]);
    }
  }
  float bias = nb[co];
  float4* dst = (float4*)(out + (size_t)(gb * 64 + co) * NL + p0 + pq * 16);
#pragma unroll
  for (int q = 0; q < 4; ++q)
    dst[q] = make_float4(acc[q * 4] + bias, acc[q * 4 + 1] + bias,
                         acc[q * 4 + 2] + bias, acc[q * 4 + 3] + bias);
}

// ---------------------------------------------------------------------------
extern "C" void kernel_launch(void* const* d_in, const int* in_sizes, int n_in,
                              void* d_out, int out_size, void* d_ws, size_t ws_size,
                              hipStream_t stream) {
  const float* x    = (const float*)d_in[0];
  const float* wip  = (const float*)d_in[1];
  const float* cwf  = (const float*)d_in[2];
  const float* cbf  = (const float*)d_in[3];
  const float* xpf  = (const float*)d_in[4];
  const float* dtwf = (const float*)d_in[5];
  const float* dtbf = (const float*)d_in[6];
  const float* Alf  = (const float*)d_in[7];
  const float* Df   = (const float*)d_in[8];
  const float* cwb  = (const float*)d_in[9];
  const float* cbb  = (const float*)d_in[10];
  const float* xpb  = (const float*)d_in[11];
  const float* dtwb = (const float*)d_in[12];
  const float* dtbb = (const float*)d_in[13];
  const float* Alb  = (const float*)d_in[14];
  const float* Db   = (const float*)d_in[15];
  const float* wout = (const float*)d_in[16];
  const float* pw   = (const float*)d_in[17];
  const float* pb   = (const float*)d_in[18];
  const float* nw   = (const float*)d_in[19];
  const float* nb   = (const float*)d_in[20];

  const size_t PER_B_BYTES = (size_t)PER_B * 4;  // 22,282,240 per batch slab
  int bcnt;
  if (ws_size >= 4 * PER_B_BYTES) bcnt = 4;
  else if (ws_size >= PER_B_BYTES) bcnt = 1;
  else return;
  int passes = 4 / bcnt;

  float* ws = (float*)d_ws;
  for (int p = 0; p < passes; ++p) {
    int b0 = p * bcnt;
    kxz   <<<dim3(256, bcnt), 256, 0, stream>>>(x, wip, ws, b0);
    k2prep<<<dim3(256, bcnt), 256, 0, stream>>>(cwf, cbf, xpf, dtwf, dtbf,
                                                cwb, cbb, xpb, dtwb, dtbb, ws);
    kscanA<<<dim3(1024, bcnt), 256, 0, stream>>>(Alf, Alb, ws);
    kscanB<<<dim3(64, bcnt), 64, 0, stream>>>(ws);
    kscanC<<<dim3(1024, bcnt), 256, 0, stream>>>(Alf, Df, Alb, Db, ws);
    koutg <<<dim3(128, bcnt), 256, 0, stream>>>(wout, ws);
    kprepw<<<dim3(27), 256, 0, stream>>>(pw, ws);
    kconv3<<<dim3(64, bcnt), 256, 0, stream>>>(pb, x, ws, b0);
    knorm <<<dim3(64, bcnt), 256, 0, stream>>>(nw, nb, (float*)d_out, ws, b0);
  }
}

// Round 4
// 265.021 us; speedup vs baseline: 1.2143x; 1.0106x over previous
//
#include <hip/hip_runtime.h>

// ---------------------------------------------------------------------------
// Bidirectional Mamba block, MI355X. Round 24:
//  - knorm FUSED into kconv3: conv block computes all 64 channels for a
//    contiguous 64-l range; conv+bias+residual staged in LDS (reuses Xs,
//    stride 65), 1x1x1 norm mix applied in-block, final output written
//    directly. Kernel + 8.4MB OX4 round-trip eliminated.
//  - koutg phase-2 -> MFMA (D[c64][l32], K=128): was 1024 serial FMA/thread.
//    Gate writes otb[l][d] bf16 transposed; o2 stored as float4 from C/D.
//  - kprepw hoisted before the pass loop; Wbf lives past the slabs.
// Shapes: B=4, C=64, D=128, L=4096 (l = h*256 + w*16 + t), N=16, R=8.
// ---------------------------------------------------------------------------

#define NL 4096

typedef unsigned short u16;
typedef unsigned int u32;
typedef __attribute__((ext_vector_type(8))) short bf16x8;
typedef __attribute__((ext_vector_type(4))) float f32x4;

__device__ __forceinline__ float siluf_(float x) {
  return x * __builtin_amdgcn_rcpf(1.f + __expf(-x));
}
__device__ __forceinline__ float softplusf_(float x) {
  return (x > 20.f) ? x : __logf(1.f + __expf(x));
}
__device__ __forceinline__ u16 f2bf(float f) {
  u32 u = __float_as_uint(f);
  u += 0x7fffu + ((u >> 16) & 1u);
  return (u16)(u >> 16);
}
__device__ __forceinline__ float bflo(u32 v) { return __uint_as_float(v << 16); }
__device__ __forceinline__ float bfhi(u32 v) { return __uint_as_float(v & 0xFFFF0000u); }

// Sum over the 16-lane DPP row via rotations 1,2,4,8 (VALU pipe, no DS).
__device__ __forceinline__ float rowsum16_(float p) {
  int q;
  q = __builtin_amdgcn_mov_dpp(__float_as_int(p), 0x121, 0xf, 0xf, false);
  p += __int_as_float(q);
  q = __builtin_amdgcn_mov_dpp(__float_as_int(p), 0x122, 0xf, 0xf, false);
  p += __int_as_float(q);
  q = __builtin_amdgcn_mov_dpp(__float_as_int(p), 0x124, 0xf, 0xf, false);
  p += __int_as_float(q);
  q = __builtin_amdgcn_mov_dpp(__float_as_int(p), 0x128, 0xf, 0xf, false);
  p += __int_as_float(q);
  return p;
}

// Per-b slab offsets (fp32 elements; bf16 regions use u16 views at same base)
#define OXZ  0u          // xz [256][4096] fp32
#define OUCF 1048576u    // ucf [128][4096] bf16 (u16 view)
#define OUCB 1572864u    // ucb [128][4096] bf16 (flipped coords)
#define ODLF 2424832u    // dlf [128][4096] bf16
#define ODLB 2949120u    // dlb [128][4096] bf16 (flipped coords)
#define OYF  3473408u    // yf [128][4096] fp32
#define OYB  3997696u    // yb [128][4096] fp32 (flipped coords)
#define OO   4521984u    // scan scratch: P [262144] S [262144] fp32
#define OO2  5046272u    // bct bf16 until kscanC; then o2 [4096][64] fp32
#define PER_B 5570560u
// Wbf [27][64][64] bf16 lives at ws + bcnt*PER_B (55296 floats)

#define NCH 64   // scan chunks
#define CL  64   // chunk length

// 1. xz[e,l] = sum_c in_proj_w[e,c] * seq[c,l].
__global__ __launch_bounds__(256) void kxz(
    const float* __restrict__ x, const float* __restrict__ wip,
    float* __restrict__ ws, int b0) {
  int bi = blockIdx.y, gb = b0 + bi;
  float* s = ws + (size_t)bi * PER_B;
  int bid = blockIdx.x;
  int h = bid >> 4, w = bid & 15;
  int tid = threadIdx.x;
  __shared__ float xs[64][16];
  for (int i = tid; i < 1024; i += 256) {
    int c = i >> 4, t = i & 15;
    xs[c][t] = x[(size_t)(gb * 64 + c) * NL + t * 256 + h * 16 + w];
  }
  __syncthreads();
  int e = tid;
  float acc[16];
#pragma unroll
  for (int t = 0; t < 16; ++t) acc[t] = 0.f;
  for (int c = 0; c < 64; ++c) {
    float wv = wip[e * 64 + c];
#pragma unroll
    for (int t = 0; t < 16; ++t) acc[t] = fmaf(wv, xs[c][t], acc[t]);
  }
  float4* dst = (float4*)(s + OXZ + (size_t)e * NL + h * 256 + w * 16);
#pragma unroll
  for (int q = 0; q < 4; ++q)
    dst[q] = make_float4(acc[q * 4], acc[q * 4 + 1], acc[q * 4 + 2], acc[q * 4 + 3]);
}

// 2. Fused prep per (bi, dir, 32-l tile): dwconv+silu, x_dbl via MFMA, delta,
// bct. Grid x = 256 (lt 128 x dir 2).
__global__ __launch_bounds__(256) void k2prep(
    const float* __restrict__ cwf, const float* __restrict__ cbf,
    const float* __restrict__ xpf, const float* __restrict__ dtwf,
    const float* __restrict__ dtbf,
    const float* __restrict__ cwb, const float* __restrict__ cbb,
    const float* __restrict__ xpb, const float* __restrict__ dtwb,
    const float* __restrict__ dtbb,
    float* __restrict__ ws) {
  int bi = blockIdx.y;
  float* s = ws + (size_t)bi * PER_B;
  int bx = blockIdx.x;
  int lt = bx >> 1, dir = bx & 1;
  int l0 = lt * 32;
  int lout0 = dir ? (127 - lt) * 32 : l0;   // output base (flipped for bwd)
  int tid = threadIdx.x;

  __shared__ float pool[128 * 40];   // X[128][40] during dwconv; xds after
  __shared__ u16 uct[32][136];       // uc transposed bf16 (d-contig, 16B rows)
  float (*X)[40] = (float(*)[40])pool;

  for (int i = tid; i < 128 * 38; i += 256) {
    int d = i / 38, j = i - d * 38;
    int l = l0 - 3 + j;
    X[d][j] = (l >= 0 && l < NL) ? s[OXZ + (size_t)d * NL + l] : 0.f;
  }
  __syncthreads();

  const float* cw = dir ? cwb : cwf;
  const float* cb = dir ? cbb : cbf;
  u16* ucg = (u16*)(s + (dir ? OUCB : OUCF));
  for (int i = tid; i < 128 * 32; i += 256) {
    int d = i >> 5, li = i & 31;
    float a = cb[d];
    if (dir == 0) {
#pragma unroll
      for (int k = 0; k < 4; ++k) a = fmaf(cw[d * 4 + k], X[d][li + k], a);
    } else {
#pragma unroll
      for (int k = 0; k < 4; ++k) a = fmaf(cw[d * 4 + k], X[d][37 - li - k], a);
    }
    a = siluf_(a);
    u16 ab = f2bf(a);
    uct[li][d] = ab;
    ucg[(size_t)d * NL + lout0 + li] = ab;
  }
  __syncthreads();  // X dead; pool becomes xds [40][33]

  // x_dbl via MFMA 16x16x32: D[e 48][l 32], K=128. Units (et,lt2) = 6 over
  // 4 waves (waves 0,1 take two units).
  float* xds = pool;
  {
    int wid = tid >> 6, lane = tid & 63;
    int n16 = lane & 15, kg = lane >> 4;
    const float* xp = dir ? xpb : xpf;
#pragma unroll
    for (int rep = 0; rep < 2; ++rep) {
      int id = wid + rep * 4;
      if (id < 6) {
        int et = id >> 1, lt2 = id & 1;
        f32x4 acc = {};
#pragma unroll
        for (int ks = 0; ks < 4; ++ks) {
          bf16x8 bfrag = *(const bf16x8*)&uct[lt2 * 16 + n16][ks * 32 + kg * 8];
          int e = et * 16 + n16;
          int ec = (e < 40) ? e : 39;        // clamp addr; rows >=40 discarded
          const float* pa = xp + ec * 128 + ks * 32 + kg * 8;
          float4 a0 = *(const float4*)pa;
          float4 a1 = *(const float4*)(pa + 4);
          bf16x8 af;
          af[0] = (short)f2bf(a0.x); af[1] = (short)f2bf(a0.y);
          af[2] = (short)f2bf(a0.z); af[3] = (short)f2bf(a0.w);
          af[4] = (short)f2bf(a1.x); af[5] = (short)f2bf(a1.y);
          af[6] = (short)f2bf(a1.z); af[7] = (short)f2bf(a1.w);
          acc = __builtin_amdgcn_mfma_f32_16x16x32_bf16(af, bfrag, acc, 0, 0, 0);
        }
        // D layout: col = lane&15 (l), row = kg*4 + rg (e within 16-tile)
#pragma unroll
        for (int rg = 0; rg < 4; ++rg) {
          int e = et * 16 + kg * 4 + rg;
          if (e < 40) xds[e * 33 + lt2 * 16 + n16] = acc[rg];
        }
      }
    }
  }
  __syncthreads();

  const float* dtw = dir ? dtwb : dtwf;
  const float* dtb = dir ? dtbb : dtbf;
  u16* dlg = (u16*)(s + (dir ? ODLB : ODLF));
  for (int i = tid; i < 128 * 32; i += 256) {
    int d = i >> 5, li = i & 31;
    float pre = dtb[d];
#pragma unroll
    for (int r = 0; r < 8; ++r)
      pre = fmaf(dtw[d * 8 + r], xds[r * 33 + li], pre);
    dlg[(size_t)d * NL + lout0 + li] = f2bf(softplusf_(pre));
  }
  u16* bctp = (u16*)(s + OO2);
  for (int i = tid; i < 32 * 32; i += 256) {
    int li = i >> 5, k = i & 31;
    bctp[((size_t)dir * 4096 + lout0 + li) * 32 + k] = f2bf(xds[(8 + k) * 33 + li]);
  }
}

// 5a. Phase A: 16 d-rows/block; chunk bct (bf16) staged to fp32 LDS;
// ushort8 dl/uc loads = 8 steps per load pair.
__global__ __launch_bounds__(256) void kscanA(
    const float* __restrict__ Alf, const float* __restrict__ Alb,
    float* __restrict__ ws) {
  int bi = blockIdx.y;
  float* s = ws + (size_t)bi * PER_B;
  int xid = blockIdx.x;
  int chunk = xid >> 4, dir = (xid >> 3) & 1, d8 = xid & 7;
  int tid = threadIdx.x;
  int wv = tid >> 6, lane = tid & 63;
  int n = lane & 15, g = lane >> 4;
  int d = d8 * 16 + wv * 4 + g;
  int l0 = chunk * CL;
  __shared__ float bl[CL * 32];
  {
    const u16* bctp = (const u16*)(s + OO2) + ((size_t)dir * 4096 + l0) * 32;
    for (int i = tid; i < CL * 32; i += 256)
      bl[i] = __uint_as_float(((u32)bctp[i]) << 16);
  }
  __syncthreads();
  const u16* ucp = (const u16*)(s + (dir ? OUCB : OUCF)) + (size_t)d * NL + l0;
  const u16* dlp = (const u16*)(s + (dir ? ODLB : ODLF)) + (size_t)d * NL + l0;
  float A = -__expf((dir ? Alb : Alf)[d * 16 + n]);
  float P = 1.f, S = 0.f;
  for (int i0 = 0; i0 < CL; i0 += 8) {
    uint4 dq = *(const uint4*)(dlp + i0);
    uint4 uq = *(const uint4*)(ucp + i0);
    float dv[8] = {bflo(dq.x), bfhi(dq.x), bflo(dq.y), bfhi(dq.y),
                   bflo(dq.z), bfhi(dq.z), bflo(dq.w), bfhi(dq.w)};
    float uv[8] = {bflo(uq.x), bfhi(uq.x), bflo(uq.y), bfhi(uq.y),
                   bflo(uq.z), bfhi(uq.z), bflo(uq.w), bfhi(uq.w)};
#pragma unroll
    for (int j = 0; j < 8; ++j) {
      float dA = __expf(dv[j] * A);
      S = fmaf(dA, S, dv[j] * bl[(i0 + j) * 32 + n] * uv[j]);
      P *= dA;
    }
  }
  size_t cidx = ((size_t)(chunk * 2 + dir) * 128 + d) * 16 + n;
  s[OO + cidx] = P;
  s[OO + 262144u + cidx] = S;
}

// 5b. Phase B: carry combine.
__global__ __launch_bounds__(64) void kscanB(float* __restrict__ ws) {
  int bi = blockIdx.y;
  float* s = ws + (size_t)bi * PER_B;
  int dir = blockIdx.x >> 5, dblk = blockIdx.x & 31;
  int tid = threadIdx.x;
  size_t base = (size_t)dir * 2048 + dblk * 64 + tid;
  float carry = 0.f;
#pragma unroll 4
  for (int c = 0; c < NCH; ++c) {
    size_t idx = (size_t)c * 4096 + base;
    float pv = s[OO + idx], sv = s[OO + 262144u + idx];
    s[OO + 262144u + idx] = carry;
    carry = fmaf(pv, carry, sv);
  }
}

// 5c. Phase C: seeded re-scan; bf16 inputs; DPP row-sum; ps[16][65] staging.
__global__ __launch_bounds__(256) void kscanC(
    const float* __restrict__ Alf, const float* __restrict__ Df,
    const float* __restrict__ Alb, const float* __restrict__ Db,
    float* __restrict__ ws) {
  int bi = blockIdx.y;
  float* s = ws + (size_t)bi * PER_B;
  int xid = blockIdx.x;
  int chunk = xid >> 4, dir = (xid >> 3) & 1, d8 = xid & 7;
  int tid = threadIdx.x;
  int wv = tid >> 6, lane = tid & 63;
  int n = lane & 15, g = lane >> 4;
  int d = d8 * 16 + wv * 4 + g;
  int l0 = chunk * CL;
  __shared__ float bl[CL * 32];
  __shared__ float ps[16][65];
  {
    const u16* bctp = (const u16*)(s + OO2) + ((size_t)dir * 4096 + l0) * 32;
    for (int i = tid; i < CL * 32; i += 256)
      bl[i] = __uint_as_float(((u32)bctp[i]) << 16);
  }
  __syncthreads();
  const u16* ucp = (const u16*)(s + (dir ? OUCB : OUCF)) + (size_t)d * NL + l0;
  const u16* dlp = (const u16*)(s + (dir ? ODLB : ODLF)) + (size_t)d * NL + l0;
  float* ybase = s + (dir ? OYB : OYF);
  float A = -__expf((dir ? Alb : Alf)[d * 16 + n]);
  float Dv = (dir ? Db : Df)[d];
  size_t cidx = ((size_t)(chunk * 2 + dir) * 128 + d) * 16 + n;
  float h = s[OO + 262144u + cidx];
  int prow = wv * 4 + g;
  for (int i0 = 0; i0 < CL; i0 += 8) {
    uint4 dq = *(const uint4*)(dlp + i0);
    uint4 uq = *(const uint4*)(ucp + i0);
    float dv[8] = {bflo(dq.x), bfhi(dq.x), bflo(dq.y), bfhi(dq.y),
                   bflo(dq.z), bfhi(dq.z), bflo(dq.w), bfhi(dq.w)};
    float uv[8] = {bflo(uq.x), bfhi(uq.x), bflo(uq.y), bfhi(uq.y),
                   bflo(uq.z), bfhi(uq.z), bflo(uq.w), bfhi(uq.w)};
#pragma unroll
    for (int j = 0; j < 8; ++j) {
      int i = i0 + j;
      float dA = __expf(dv[j] * A);
      h = fmaf(dA, h, dv[j] * bl[i * 32 + n] * uv[j]);
      float p = rowsum16_(h * bl[i * 32 + 16 + n]);
      if (n == 0) ps[prow][i] = fmaf(uv[j], Dv, p);
    }
  }
  __syncthreads();
  for (int i = tid; i < 16 * CL; i += 256) {
    int row = i >> 6, col = i & 63;
    ybase[(size_t)(d8 * 16 + row) * NL + l0 + col] = ps[row][col];
  }
}

// 6. Fused gate + out-proj via MFMA. Block = 32-l tile.
// Gate: otb[l 32][d 128 pad 136] bf16 (transposed, 16B rows). Out-proj:
// D[c 64][l 32], K=128; wave ct handles both l2 tiles; float4 stores.
__global__ __launch_bounds__(256) void koutg(
    const float* __restrict__ wout, float* __restrict__ ws) {
  int bi = blockIdx.y;
  float* s = ws + (size_t)bi * PER_B;
  int lt = blockIdx.x;
  int l0 = lt * 32;
  int tid = threadIdx.x;
  __shared__ u16 otb[32][136];
  for (int i = tid; i < 128 * 32; i += 256) {
    int d = i >> 5, li = i & 31;
    int l = l0 + li;
    float z = s[OXZ + (size_t)(128 + d) * NL + l];
    float v = s[OYF + (size_t)d * NL + l] + s[OYB + (size_t)d * NL + (NL - 1 - l)];
    otb[li][d] = f2bf(v * siluf_(z));
  }
  __syncthreads();
  int wid = tid >> 6, lane = tid & 63;
  int n16 = lane & 15, kg = lane >> 4;
  f32x4 acc[2] = {};   // [l2 tile]
  const float* wr = wout + (size_t)(wid * 16 + n16) * 128 + kg * 8;
#pragma unroll
  for (int ks = 0; ks < 4; ++ks) {
    const float* pa = wr + ks * 32;
    float4 a0 = *(const float4*)pa;
    float4 a1 = *(const float4*)(pa + 4);
    bf16x8 af;
    af[0] = (short)f2bf(a0.x); af[1] = (short)f2bf(a0.y);
    af[2] = (short)f2bf(a0.z); af[3] = (short)f2bf(a0.w);
    af[4] = (short)f2bf(a1.x); af[5] = (short)f2bf(a1.y);
    af[6] = (short)f2bf(a1.z); af[7] = (short)f2bf(a1.w);
    bf16x8 b0 = *(const bf16x8*)&otb[n16][ks * 32 + kg * 8];
    bf16x8 b1 = *(const bf16x8*)&otb[16 + n16][ks * 32 + kg * 8];
    acc[0] = __builtin_amdgcn_mfma_f32_16x16x32_bf16(af, b0, acc[0], 0, 0, 0);
    acc[1] = __builtin_amdgcn_mfma_f32_16x16x32_bf16(af, b1, acc[1], 0, 0, 0);
  }
  // D: col = lane&15 (l), row = kg*4+rg (c in 16-tile); rg = consecutive c.
#pragma unroll
  for (int l2 = 0; l2 < 2; ++l2) {
    float4 st = make_float4(acc[l2][0], acc[l2][1], acc[l2][2], acc[l2][3]);
    *(float4*)&s[OO2 + (size_t)(l0 + l2 * 16 + n16) * 64 + wid * 16 + kg * 4] = st;
  }
}

// 6.5. Weight prep: Wbf[27][co 64][ci 64] bf16 at ws + bcnt*PER_B.
__global__ __launch_bounds__(256) void kprepw(
    const float* __restrict__ pw, float* __restrict__ wdst) {
  int off = blockIdx.x;
  u16* wb = (u16*)wdst;
  int tid = threadIdx.x;
  for (int i = tid; i < 4096; i += 256) {
    int co = i >> 6, ci = i & 63;
    wb[off * 4096 + i] = f2bf(pw[(size_t)(co * 64 + ci) * 27 + off]);
  }
}

// 7. conv3d (bf16 implicit GEMM on MFMA) + FUSED 1x1x1 norm mix.
// Block tile [64 co][64 l] = one t-plane x 4 h-rows; grid = t(16) x hq(4).
// After MFMA: cx[ci 64][lp 64 pad 65] fp32 = conv+bias+residual in LDS
// (overlays dead Xs), then out[co] = nb + sum_ci nw[co,ci]*cx[ci] -> global.
__global__ __launch_bounds__(256) void kconv3(
    const float* __restrict__ pb, const float* __restrict__ nw,
    const float* __restrict__ nb, const float* __restrict__ xin,
    float* __restrict__ out, const u16* __restrict__ wb,
    float* __restrict__ ws, int b0) {
  int bi = blockIdx.y, gb = b0 + bi;
  float* s = ws + (size_t)bi * PER_B;
  int t = blockIdx.x >> 2, hq = blockIdx.x & 3;
  int h0 = hq * 4;
  int tid = threadIdx.x;
  const float* xr = s + OO2;              // o2 in c'-major view [64][4096]

  __shared__ u16 Xs[3 * 6 * 18 * 72];     // 46656 B; later aliased as cx
  float* cx = (float*)Xs;                 // cx[64][65] = 16640 B
  // zero (covers t/h/w halo padding)
  {
    u32* xz32 = (u32*)Xs;
    for (int i = tid; i < 3 * 6 * 18 * 72 / 2; i += 256) xz32[i] = 0u;
  }
  __syncthreads();
  // stage valid rows, transposed to ci-contiguous bf16
  {
    int ci = tid >> 2, wq = tid & 3;
    for (int row = 0; row < 18; ++row) {
      int tt = row / 6, hh = row - tt * 6;
      int ts = t + tt - 1, hs = h0 + hh - 1;
      if (ts < 0 || ts > 15 || hs < 0 || hs > 15) continue;
      float4 v = *(const float4*)(xr + (size_t)ci * NL + ts * 256 + hs * 16 + wq * 4);
      int rb = (tt * 6 + hh) * 18 + 1 + wq * 4;
      Xs[(rb + 0) * 72 + ci] = f2bf(v.x);
      Xs[(rb + 1) * 72 + ci] = f2bf(v.y);
      Xs[(rb + 2) * 72 + ci] = f2bf(v.z);
      Xs[(rb + 3) * 72 + ci] = f2bf(v.w);
    }
  }
  __syncthreads();

  int wid = tid >> 6, lane = tid & 63;
  int cb = wid >> 1, lb = wid & 1;
  int n16 = lane & 15, kg = lane >> 4;   // k-group 0..3 (8 ci each)
  f32x4 acc[2][2] = {};                  // [c2 co-subtile][l2 l-subtile]

  // A: Wbf[off][co][ci]; lane row co = cb*32 + c2*16 + n16, k = kg*8+st*32+j
  const u16* wbA = wb + (size_t)(cb * 32 + n16) * 64 + kg * 8;
  for (int kt = 0; kt < 3; ++kt)
    for (int kh = 0; kh < 3; ++kh) {
      int rbase = (kt * 6 + lb * 2 + kh) * 18 + n16;
#pragma unroll
      for (int kw = 0; kw < 3; ++kw) {
        int off = (kt * 3 + kh) * 3 + kw;
        int r0 = rbase + kw;       // l2=0 spatial row
        const u16* pa = wbA + off * 4096;
#pragma unroll
        for (int st = 0; st < 2; ++st) {
          int kb = st * 32;
          bf16x8 a0 = *(const bf16x8*)(pa + kb);
          bf16x8 a1 = *(const bf16x8*)(pa + 16 * 64 + kb);
          bf16x8 b0 = *(const bf16x8*)(&Xs[r0 * 72 + kb + kg * 8]);
          bf16x8 b1 = *(const bf16x8*)(&Xs[(r0 + 18) * 72 + kb + kg * 8]);
          acc[0][0] = __builtin_amdgcn_mfma_f32_16x16x32_bf16(a0, b0, acc[0][0], 0, 0, 0);
          acc[0][1] = __builtin_amdgcn_mfma_f32_16x16x32_bf16(a0, b1, acc[0][1], 0, 0, 0);
          acc[1][0] = __builtin_amdgcn_mfma_f32_16x16x32_bf16(a1, b0, acc[1][0], 0, 0, 0);
          acc[1][1] = __builtin_amdgcn_mfma_f32_16x16x32_bf16(a1, b1, acc[1][1], 0, 0, 0);
        }
      }
    }
  __syncthreads();  // all Xs reads done; safe to overwrite with cx

  // cx[co][lp] = conv + bias + residual.
  // C/D layout: col = lane&15 (w), row = kg*4 + reg (co within 16-subtile)
#pragma unroll
  for (int c2 = 0; c2 < 2; ++c2) {
#pragma unroll
    for (int l2 = 0; l2 < 2; ++l2) {
      int lp = (lb * 2 + l2) * 16 + n16;
      int lg = t * 256 + h0 * 16 + lp;
#pragma unroll
      for (int rg = 0; rg < 4; ++rg) {
        int co = cb * 32 + c2 * 16 + kg * 4 + rg;
        cx[co * 65 + lp] = acc[c2][l2][rg] + pb[co] +
                           xin[(size_t)(gb * 64 + co) * NL + lg];
      }
    }
  }
  __syncthreads();

  // 1x1x1 norm mix: out[co2][lp] = nb + sum_ci nw[co2,ci] * cx[ci][lp]
  {
    int co2 = tid >> 2, pq = tid & 3;
    float mac[16];
#pragma unroll
    for (int j = 0; j < 16; ++j) mac[j] = 0.f;
    for (int ci = 0; ci < 64; ci += 4) {
      float4 w4 = *(const float4*)&nw[co2 * 64 + ci];
      float wv[4] = {w4.x, w4.y, w4.z, w4.w};
#pragma unroll
      for (int cc = 0; cc < 4; ++cc) {
        const float* row = &cx[(ci + cc) * 65 + pq * 16];
        float4 a = *(const float4*)&row[0];
        float4 b = *(const float4*)&row[4];
        float4 c = *(const float4*)&row[8];
        float4 e = *(const float4*)&row[12];
        mac[0] = fmaf(wv[cc], a.x, mac[0]);   mac[1] = fmaf(wv[cc], a.y, mac[1]);
        mac[2] = fmaf(wv[cc], a.z, mac[2]);   mac[3] = fmaf(wv[cc], a.w, mac[3]);
        mac[4] = fmaf(wv[cc], b.x, mac[4]);   mac[5] = fmaf(wv[cc], b.y, mac[5]);
        mac[6] = fmaf(wv[cc], b.z, mac[6]);   mac[7] = fmaf(wv[cc], b.w, mac[7]);
        mac[8] = fmaf(wv[cc], c.x, mac[8]);   mac[9] = fmaf(wv[cc], c.y, mac[9]);
        mac[10] = fmaf(wv[cc], c.z, mac[10]); mac[11] = fmaf(wv[cc], c.w, mac[11]);
        mac[12] = fmaf(wv[cc], e.x, mac[12]); mac[13] = fmaf(wv[cc], e.y, mac[13]);
        mac[14] = fmaf(wv[cc], e.z, mac[14]); mac[15] = fmaf(wv[cc], e.w, mac[15]);
      }
    }
    float bias = nb[co2];
    float4* dst = (float4*)(out + (size_t)(gb * 64 + co2) * NL +
                            t * 256 + h0 * 16 + pq * 16);
#pragma unroll
    for (int q = 0; q < 4; ++q)
      dst[q] = make_float4(mac[q * 4] + bias, mac[q * 4 + 1] + bias,
                           mac[q * 4 + 2] + bias, mac[q * 4 + 3] + bias);
  }
}

// ---------------------------------------------------------------------------
extern "C" void kernel_launch(void* const* d_in, const int* in_sizes, int n_in,
                              void* d_out, int out_size, void* d_ws, size_t ws_size,
                              hipStream_t stream) {
  const float* x    = (const float*)d_in[0];
  const float* wip  = (const float*)d_in[1];
  const float* cwf  = (const float*)d_in[2];
  const float* cbf  = (const float*)d_in[3];
  const float* xpf  = (const float*)d_in[4];
  const float* dtwf = (const float*)d_in[5];
  const float* dtbf = (const float*)d_in[6];
  const float* Alf  = (const float*)d_in[7];
  const float* Df   = (const float*)d_in[8];
  const float* cwb  = (const float*)d_in[9];
  const float* cbb  = (const float*)d_in[10];
  const float* xpb  = (const float*)d_in[11];
  const float* dtwb = (const float*)d_in[12];
  const float* dtbb = (const float*)d_in[13];
  const float* Alb  = (const float*)d_in[14];
  const float* Db   = (const float*)d_in[15];
  const float* wout = (const float*)d_in[16];
  const float* pw   = (const float*)d_in[17];
  const float* pb   = (const float*)d_in[18];
  const float* nw   = (const float*)d_in[19];
  const float* nb   = (const float*)d_in[20];

  const size_t PER_B_BYTES = (size_t)PER_B * 4;  // 22,282,240 per batch slab
  const size_t WB_BYTES = 27u * 64u * 64u * 2u;  // 221,184 (Wbf bf16)
  int bcnt;
  if (ws_size >= 4 * PER_B_BYTES + WB_BYTES) bcnt = 4;
  else if (ws_size >= PER_B_BYTES + WB_BYTES) bcnt = 1;
  else return;
  int passes = 4 / bcnt;

  float* ws = (float*)d_ws;
  float* wsW = ws + (size_t)bcnt * PER_B;
  kprepw<<<dim3(27), 256, 0, stream>>>(pw, wsW);
  for (int p = 0; p < passes; ++p) {
    int b0 = p * bcnt;
    kxz   <<<dim3(256, bcnt), 256, 0, stream>>>(x, wip, ws, b0);
    k2prep<<<dim3(256, bcnt), 256, 0, stream>>>(cwf, cbf, xpf, dtwf, dtbf,
                                                cwb, cbb, xpb, dtwb, dtbb, ws);
    kscanA<<<dim3(1024, bcnt), 256, 0, stream>>>(Alf, Alb, ws);
    kscanB<<<dim3(64, bcnt), 64, 0, stream>>>(ws);
    kscanC<<<dim3(1024, bcnt), 256, 0, stream>>>(Alf, Df, Alb, Db, ws);
    koutg <<<dim3(128, bcnt), 256, 0, stream>>>(wout, ws);
    kconv3<<<dim3(64, bcnt), 256, 0, stream>>>(pb, nw, nb, x, (float*)d_out,
                                               (const u16*)wsW, ws, b0);
  }
}